// Round 1
// baseline (1347.767 us; speedup 1.0000x reference)
//
#include <hip/hip_runtime.h>

// EncodingBlock (ST-GCN style) — Round 1: full-f32 correctness baseline.
// Pipeline:
//  k1: per-(n,t) fused LN + QK proj + dots/softmax*topo + z=A@feat + sa=z@Wcat (+bias)
//      -> saRaw (=d_out scratch) + per-channel partial sums for sagc BN
//  k2: reduce -> sagc BN scale/shift
//  k3: y_gc = relu(bn(sa)+x); pre = y_gc @ W1 + b1 -> preRaw + partials for bn1
//  k4: reduce -> bn1 scale/shift
//  k5: act=relu(bn1(pre[:, :3])); dilated conv5 (d=1,2) + maxpool3 -> zbRaw + partials bn2
//  k6: reduce -> bn2 scale/shift
//  k7: concat [conv1, conv2, pool, pre3] with bn applied, + x, relu -> out
// Workspace: 48,071,008 floats = 183.4 MiB.

#define EPS 1e-5f

// ------------------------------------------------------------------
// Kernel 1: fused SelfAttention + SA_GC (pre-BN), one block per (n,t)
// ------------------------------------------------------------------
__global__ __launch_bounds__(256, 2)
void k1_sa_sagc(const float* __restrict__ x,
                const float* __restrict__ topo,
                const float* __restrict__ ln_g, const float* __restrict__ ln_b,
                const float* __restrict__ qk_w, const float* __restrict__ qk_b,
                const float* __restrict__ convd_w, const float* __restrict__ convd_b,
                float* __restrict__ saRaw, float* __restrict__ pSum, float* __restrict__ pSq)
{
  const int t = blockIdx.x, n = blockIdx.y, tid = threadIdx.x;
  const int blk = n * 512 + t;

  __shared__ __align__(16) float uni[9814];      // phaseA union / W2-half / sSa
  __shared__ __align__(16) float sZ[25 * 196];   // z concat [i][h*64+c]
  __shared__ float sMu[25], sRstd[25];

  float* sFeat = uni;           // [25][68]
  float* sY    = uni + 1700;    // [25][68]
  float* sQKW  = uni + 3400;    // [48][68]  qk_w natural [m][c]
  float* sQK   = uni + 6664;    // [25][48]
  float* sAttn = uni + 7864;    // [3][25][26]

  // (1) x tile -> feat[v][c]
  for (int idx = tid; idx < 1600; idx += 256) {
    int c = idx / 25, v = idx - c * 25;
    sFeat[v * 68 + c] = x[((n * 64 + c) * 512 + t) * 25 + v];
  }
  __syncthreads();

  // (2) LayerNorm stats (8 lanes per row)
  {
    int r = tid >> 3, sub = tid & 7;
    if (r < 25) {
      float s = 0.f, q = 0.f;
      #pragma unroll
      for (int c = 0; c < 64; c += 8) { float f = sFeat[r * 68 + c + sub]; s += f; q += f * f; }
      s += __shfl_xor(s, 1); q += __shfl_xor(q, 1);
      s += __shfl_xor(s, 2); q += __shfl_xor(q, 2);
      s += __shfl_xor(s, 4); q += __shfl_xor(q, 4);
      if (sub == 0) {
        float mu = s * (1.f / 64.f);
        float var = q * (1.f / 64.f) - mu * mu;
        sMu[r] = mu; sRstd[r] = rsqrtf(var + EPS);
      }
    }
  }
  // stage qk_w (coalesced read, conflict-free row write)
  for (int idx = tid; idx < 3072; idx += 256) {
    int m = idx >> 6, c = idx & 63;
    sQKW[m * 68 + c] = qk_w[idx];
  }
  __syncthreads();

  // (3) y = LN(feat)
  for (int idx = tid; idx < 1600; idx += 256) {
    int v = idx >> 6, c = idx & 63;
    sY[v * 68 + c] = (sFeat[v * 68 + c] - sMu[v]) * sRstd[v] * ln_g[c] + ln_b[c];
  }
  __syncthreads();

  // (4) qk[i][m] = y[i][:] . qk_w[m][:] + qk_b[m]; thread owns row m, 5 i's
  if (tid < 240) {
    int m = tid % 48, grp = tid / 48;
    float acc0, acc1, acc2, acc3, acc4;
    { float bb = qk_b[m]; acc0 = acc1 = acc2 = acc3 = acc4 = bb; }
    for (int c0 = 0; c0 < 64; c0 += 16) {
      const float* wr = &sQKW[m * 68 + c0];
      float4 wa = *(const float4*)wr, wb = *(const float4*)(wr + 4);
      float4 wc = *(const float4*)(wr + 8), wd = *(const float4*)(wr + 12);
      #pragma unroll
      for (int r = 0; r < 5; r++) {
        int i = grp + 5 * r;
        const float* yr = &sY[i * 68 + c0];
        float4 ya = *(const float4*)yr, yb = *(const float4*)(yr + 4);
        float4 yc = *(const float4*)(yr + 8), yd = *(const float4*)(yr + 12);
        float d = ya.x * wa.x + ya.y * wa.y + ya.z * wa.z + ya.w * wa.w
                + yb.x * wb.x + yb.y * wb.y + yb.z * wb.z + yb.w * wb.w
                + yc.x * wc.x + yc.y * wc.y + yc.z * wc.z + yc.w * wc.w
                + yd.x * wd.x + yd.y * wd.y + yd.z * wd.z + yd.w * wd.w;
        if (r == 0) acc0 += d; else if (r == 1) acc1 += d; else if (r == 2) acc2 += d;
        else if (r == 3) acc3 += d; else acc4 += d;
      }
    }
    sQK[(grp     ) * 48 + m] = acc0;
    sQK[(grp +  5) * 48 + m] = acc1;
    sQK[(grp + 10) * 48 + m] = acc2;
    sQK[(grp + 15) * 48 + m] = acc3;
    sQK[(grp + 20) * 48 + m] = acc4;
  }
  __syncthreads();

  // (5) dots + softmax + *topo  (one thread per (h,i) row)
  if (tid < 75) {
    int h = tid / 25, i = tid - (tid / 25) * 25;
    const float* qr = &sQK[i * 48 + h * 8];
    float4 qa = *(const float4*)qr, qb = *(const float4*)(qr + 4);
    float lgv[25];
    float lmax = -3.4e38f;
    #pragma unroll
    for (int j = 0; j < 25; j++) {
      const float* kr = &sQK[j * 48 + 24 + h * 8];
      float4 ka = *(const float4*)kr, kb = *(const float4*)(kr + 4);
      float d = qa.x * ka.x + qa.y * ka.y + qa.z * ka.z + qa.w * ka.w
              + qb.x * kb.x + qb.y * kb.y + qb.z * kb.z + qb.w * kb.w;
      d *= 0.35355339059327373f;   // 8^-0.5
      lgv[j] = d;
      lmax = fmaxf(lmax, d);
    }
    float se = 0.f;
    #pragma unroll
    for (int j = 0; j < 25; j++) { float e = __expf(lgv[j] - lmax); lgv[j] = e; se += e; }
    float inv = 1.f / se;
    #pragma unroll
    for (int j = 0; j < 25; j++)
      sAttn[(h * 25 + i) * 26 + j] = lgv[j] * inv * topo[(h * 25 + i) * 25 + j];
  }
  __syncthreads();

  // (6) z[i][h*64+c] = sum_j A[h][i][j] * feat[j][c]   (thread: i = tid/8, c8 = (tid&7)*8)
  if ((tid >> 3) < 25) {
    int i = tid >> 3, c8 = (tid & 7) * 8;
    float acc[3][8];
    #pragma unroll
    for (int h = 0; h < 3; h++)
      #pragma unroll
      for (int e = 0; e < 8; e++) acc[h][e] = 0.f;
    for (int j = 0; j < 25; j++) {
      const float* fr = &sFeat[j * 68 + c8];
      float4 fa = *(const float4*)fr, fb = *(const float4*)(fr + 4);
      #pragma unroll
      for (int h = 0; h < 3; h++) {
        float a = sAttn[(h * 25 + i) * 26 + j];
        acc[h][0] += a * fa.x; acc[h][1] += a * fa.y; acc[h][2] += a * fa.z; acc[h][3] += a * fa.w;
        acc[h][4] += a * fb.x; acc[h][5] += a * fb.y; acc[h][6] += a * fb.z; acc[h][7] += a * fb.w;
      }
    }
    #pragma unroll
    for (int h = 0; h < 3; h++) {
      float* zr = &sZ[i * 196 + h * 64 + c8];
      *(float4*)zr       = make_float4(acc[h][0], acc[h][1], acc[h][2], acc[h][3]);
      *(float4*)(zr + 4) = make_float4(acc[h][4], acc[h][5], acc[h][6], acc[h][7]);
    }
  }
  __syncthreads();

  // (7) sa[i][o] = sum_k z[i][k] * Wcat[k][o] + sum_h convd_b[h][o]; two k-half passes
  int tx = tid & 15, o4 = tx * 4, ty = tid >> 4;
  float acc[2][4];
  {
    float4 b0 = *(const float4*)&convd_b[o4];
    float4 b1v = *(const float4*)&convd_b[64 + o4];
    float4 b2v = *(const float4*)&convd_b[128 + o4];
    float s0 = b0.x + b1v.x + b2v.x, s1 = b0.y + b1v.y + b2v.y;
    float s2 = b0.z + b1v.z + b2v.z, s3 = b0.w + b1v.w + b2v.w;
    acc[0][0] = acc[1][0] = s0; acc[0][1] = acc[1][1] = s1;
    acc[0][2] = acc[1][2] = s2; acc[0][3] = acc[1][3] = s3;
  }
  float* sW2h = uni;   // [96][68]
  for (int pass = 0; pass < 2; pass++) {
    __syncthreads();
    for (int idx = tid; idx < 6144; idx += 256) {
      int kk = idx >> 6, o = idx & 63;
      int k = pass * 96 + kk, h = k >> 6, c = k & 63;
      sW2h[kk * 68 + o] = convd_w[(h * 64 + o) * 64 + c];
    }
    __syncthreads();
    for (int kk = 0; kk < 96; kk += 4) {
      float4 w0 = *(const float4*)&sW2h[(kk + 0) * 68 + o4];
      float4 w1v = *(const float4*)&sW2h[(kk + 1) * 68 + o4];
      float4 w2v = *(const float4*)&sW2h[(kk + 2) * 68 + o4];
      float4 w3v = *(const float4*)&sW2h[(kk + 3) * 68 + o4];
      #pragma unroll
      for (int r = 0; r < 2; r++) {
        int i = ty + 16 * r;
        if (i < 25) {
          float4 z4 = *(const float4*)&sZ[i * 196 + pass * 96 + kk];
          acc[r][0] += z4.x * w0.x + z4.y * w1v.x + z4.z * w2v.x + z4.w * w3v.x;
          acc[r][1] += z4.x * w0.y + z4.y * w1v.y + z4.z * w2v.y + z4.w * w3v.y;
          acc[r][2] += z4.x * w0.z + z4.y * w1v.z + z4.z * w2v.z + z4.w * w3v.z;
          acc[r][3] += z4.x * w0.w + z4.y * w1v.w + z4.z * w2v.w + z4.w * w3v.w;
        }
      }
    }
  }
  __syncthreads();
  float* sSa = uni;   // [64][29]
  #pragma unroll
  for (int r = 0; r < 2; r++) {
    int i = ty + 16 * r;
    if (i < 25) {
      #pragma unroll
      for (int j = 0; j < 4; j++) sSa[(o4 + j) * 29 + i] = acc[r][j];
    }
  }
  __syncthreads();
  for (int idx = tid; idx < 1600; idx += 256) {
    int o = idx / 25, i2 = idx - o * 25;
    saRaw[((n * 64 + o) * 512 + t) * 25 + i2] = sSa[o * 29 + i2];
  }
  if (tid < 64) {
    float s = 0.f, q = 0.f;
    #pragma unroll
    for (int i = 0; i < 25; i++) { float v = sSa[tid * 29 + i]; s += v; q += v * v; }
    pSum[tid * 16384 + blk] = s;
    pSq [tid * 16384 + blk] = q;
  }
}

// ------------------------------------------------------------------
// Generic BN-stat reduce: one block per channel
// ------------------------------------------------------------------
__global__ __launch_bounds__(256, 4)
void kreduce(const float* __restrict__ pS, const float* __restrict__ pQ, int npart, float invN,
             const float* __restrict__ g, const float* __restrict__ bta,
             float* __restrict__ sc, float* __restrict__ sh)
{
  int c = blockIdx.x, tid = threadIdx.x;
  float s = 0.f, q = 0.f;
  for (int i = tid; i < npart; i += 256) { s += pS[c * npart + i]; q += pQ[c * npart + i]; }
  #pragma unroll
  for (int m = 1; m < 64; m <<= 1) { s += __shfl_xor(s, m); q += __shfl_xor(q, m); }
  __shared__ float rs[4], rq[4];
  int w = tid >> 6;
  if ((tid & 63) == 0) { rs[w] = s; rq[w] = q; }
  __syncthreads();
  if (tid == 0) {
    float S = rs[0] + rs[1] + rs[2] + rs[3];
    float Q = rq[0] + rq[1] + rq[2] + rq[3];
    float mu = S * invN, var = Q * invN - mu * mu;
    float r = rsqrtf(var + EPS);
    sc[c] = g[c] * r;
    sh[c] = bta[c] - mu * g[c] * r;
  }
}

// ------------------------------------------------------------------
// Kernel 3: y_gc = relu(bn(sa)+x); pre = y_gc @ W1 + b1; partials for bn1
// ------------------------------------------------------------------
__global__ __launch_bounds__(256, 2)
void k3_ygc_pre(const float* __restrict__ x, const float* __restrict__ saRaw,
                const float* __restrict__ scS, const float* __restrict__ shS,
                const float* __restrict__ w1g, const float* __restrict__ b1,
                float* __restrict__ preRaw, float* __restrict__ pSum, float* __restrict__ pSq)
{
  const int t = blockIdx.x, n = blockIdx.y, tid = threadIdx.x;
  const int blk = n * 512 + t;
  __shared__ __align__(16) float sYgc[25 * 68];
  __shared__ __align__(16) float sW1[64 * 68];   // [c][ko]
  __shared__ float sPre[64 * 29];

  for (int idx = tid; idx < 1600; idx += 256) {
    int c = idx / 25, v = idx - c * 25;
    int a = ((n * 64 + c) * 512 + t) * 25 + v;
    float val = scS[c] * saRaw[a] + shS[c] + x[a];
    sYgc[v * 68 + c] = fmaxf(val, 0.f);
  }
  for (int idx = tid; idx < 4096; idx += 256) {
    int c = idx >> 6, ko = idx & 63;
    sW1[c * 68 + ko] = w1g[ko * 64 + c];
  }
  __syncthreads();

  int tx = tid & 15, o4 = tx * 4, ty = tid >> 4;
  float acc[2][4];
  { float4 bb = *(const float4*)&b1[o4];
    acc[0][0] = acc[1][0] = bb.x; acc[0][1] = acc[1][1] = bb.y;
    acc[0][2] = acc[1][2] = bb.z; acc[0][3] = acc[1][3] = bb.w; }
  for (int c0 = 0; c0 < 64; c0 += 4) {
    float4 w0  = *(const float4*)&sW1[(c0 + 0) * 68 + o4];
    float4 wv1 = *(const float4*)&sW1[(c0 + 1) * 68 + o4];
    float4 wv2 = *(const float4*)&sW1[(c0 + 2) * 68 + o4];
    float4 wv3 = *(const float4*)&sW1[(c0 + 3) * 68 + o4];
    #pragma unroll
    for (int r = 0; r < 2; r++) {
      int i = ty + 16 * r;
      if (i < 25) {
        float4 a4 = *(const float4*)&sYgc[i * 68 + c0];
        acc[r][0] += a4.x * w0.x + a4.y * wv1.x + a4.z * wv2.x + a4.w * wv3.x;
        acc[r][1] += a4.x * w0.y + a4.y * wv1.y + a4.z * wv2.y + a4.w * wv3.y;
        acc[r][2] += a4.x * w0.z + a4.y * wv1.z + a4.z * wv2.z + a4.w * wv3.z;
        acc[r][3] += a4.x * w0.w + a4.y * wv1.w + a4.z * wv2.w + a4.w * wv3.w;
      }
    }
  }
  #pragma unroll
  for (int r = 0; r < 2; r++) {
    int i = ty + 16 * r;
    if (i < 25) {
      #pragma unroll
      for (int j = 0; j < 4; j++) sPre[(o4 + j) * 29 + i] = acc[r][j];
    }
  }
  __syncthreads();
  for (int idx = tid; idx < 1600; idx += 256) {
    int ko = idx / 25, v = idx - ko * 25;
    preRaw[((n * 64 + ko) * 512 + t) * 25 + v] = sPre[ko * 29 + v];
  }
  if (tid < 64) {
    float s = 0.f, q = 0.f;
    #pragma unroll
    for (int i = 0; i < 25; i++) { float v = sPre[tid * 29 + i]; s += v; q += v * v; }
    pSum[tid * 16384 + blk] = s;
    pSq [tid * 16384 + blk] = q;
  }
}

// ------------------------------------------------------------------
// Kernel 5: TCN branches (dilated conv5 d=1,2 and maxpool3), + bn2 partials
// ------------------------------------------------------------------
template<int D>
__device__ __forceinline__ void conv5(const float* __restrict__ sIn, const float* __restrict__ sW,
                                      float4 bias, int o4, int v, int tb, float acc[8][4])
{
  #pragma unroll
  for (int s = 0; s < 8; s++) {
    acc[s][0] = bias.x; acc[s][1] = bias.y; acc[s][2] = bias.z; acc[s][3] = bias.w;
  }
  const int NW = 8 + 4 * D;
  for (int ic = 0; ic < 16; ic++) {
    float4 wk[5];
    #pragma unroll
    for (int kt = 0; kt < 5; kt++) wk[kt] = *(const float4*)&sW[(ic * 5 + kt) * 16 + o4];
    float xw[8 + 4 * D];
    #pragma unroll
    for (int w = 0; w < NW; w++) xw[w] = sIn[(ic * 24 + (tb - 2 * D + w + 4)) * 25 + v];
    #pragma unroll
    for (int s = 0; s < 8; s++)
      #pragma unroll
      for (int kt = 0; kt < 5; kt++) {
        float xv = xw[s + kt * D];
        acc[s][0] += xv * wk[kt].x; acc[s][1] += xv * wk[kt].y;
        acc[s][2] += xv * wk[kt].z; acc[s][3] += xv * wk[kt].w;
      }
  }
}

__global__ __launch_bounds__(256, 2)
void k5_tcn_branch(const float* __restrict__ preRaw,
                   const float* __restrict__ sc1, const float* __restrict__ sh1,
                   const float* __restrict__ w2, const float* __restrict__ b2,
                   float* __restrict__ zbRaw, float* __restrict__ pSum2, float* __restrict__ pSq2)
{
  const int tt = blockIdx.x, b = blockIdx.y, n = blockIdx.z;
  const int tid = threadIdx.x, t0 = tt * 16;
  __shared__ __align__(16) float sIn[16 * 24 * 25];
  __shared__ __align__(16) float sW[16 * 5 * 16];
  __shared__ float sRedS[4][4][4], sRedQ[4][4][4];

  for (int idx = tid; idx < 9600; idx += 256) {
    int ic = idx / 600, rr = idx - ic * 600;
    int r = rr / 25, v = rr - r * 25;
    int gt = t0 - 4 + r, ch = b * 16 + ic;
    float val = 0.f;
    if (gt >= 0 && gt < 512)
      val = fmaxf(sc1[ch] * preRaw[((n * 64 + ch) * 512 + gt) * 25 + v] + sh1[ch], 0.f);
    sIn[(ic * 24 + r) * 25 + v] = val;
  }
  if (b < 2)
    for (int idx = tid; idx < 1280; idx += 256) {
      int o = idx / 80, rem = idx - o * 80;
      int ic = rem / 5, kt = rem - ic * 5;
      sW[(ic * 5 + kt) * 16 + o] = w2[((b * 16 + o) * 16 + ic) * 5 + kt];
    }
  __syncthreads();

  float po[4] = {0.f, 0.f, 0.f, 0.f}, pq[4] = {0.f, 0.f, 0.f, 0.f};
  if (tid < 200) {
    int tx = tid & 3, o4 = tx * 4;
    int g = tid >> 2;
    int v = g % 25, th = g / 25;
    int tb = th * 8;
    float acc[8][4];
    if (b == 0)      conv5<1>(sIn, sW, *(const float4*)&b2[o4],      o4, v, tb, acc);
    else if (b == 1) conv5<2>(sIn, sW, *(const float4*)&b2[16 + o4], o4, v, tb, acc);
    else {
      #pragma unroll
      for (int s = 0; s < 8; s++)
        #pragma unroll
        for (int j = 0; j < 4; j++) {
          int o = o4 + j, r = tb + s + 4;
          float a = sIn[(o * 24 + r - 1) * 25 + v];
          float m = sIn[(o * 24 + r    ) * 25 + v];
          float c = sIn[(o * 24 + r + 1) * 25 + v];
          acc[s][j] = fmaxf(fmaxf(a, m), c);
        }
    }
    #pragma unroll
    for (int s = 0; s < 8; s++) {
      int gt = t0 + tb + s;
      #pragma unroll
      for (int j = 0; j < 4; j++) {
        float val = acc[s][j];
        zbRaw[(((b * 32 + n) * 16 + (o4 + j)) * 512 + gt) * 25 + v] = val;
        po[j] += val; pq[j] += val * val;
      }
    }
  }
  #pragma unroll
  for (int m = 4; m < 64; m <<= 1) {
    #pragma unroll
    for (int j = 0; j < 4; j++) { po[j] += __shfl_xor(po[j], m); pq[j] += __shfl_xor(pq[j], m); }
  }
  int lane = tid & 63, w = tid >> 6;
  if (lane < 4) {
    #pragma unroll
    for (int j = 0; j < 4; j++) { sRedS[w][lane][j] = po[j]; sRedQ[w][lane][j] = pq[j]; }
  }
  __syncthreads();
  if (tid < 16) {
    int o = tid, txo = o >> 2, j = o & 3;
    float s = 0.f, q = 0.f;
    #pragma unroll
    for (int ww = 0; ww < 4; ww++) { s += sRedS[ww][txo][j]; q += sRedQ[ww][txo][j]; }
    int pidx = (b * 16 + o) * 1024 + (n * 32 + tt);
    pSum2[pidx] = s; pSq2[pidx] = q;
  }
}

// ------------------------------------------------------------------
// Kernel 7: concat branches + bn + residual + relu
// ------------------------------------------------------------------
__global__ __launch_bounds__(256, 4)
void k7_final(const float* __restrict__ x, const float* __restrict__ preRaw,
              const float* __restrict__ zbRaw,
              const float* __restrict__ sc1, const float* __restrict__ sh1,
              const float* __restrict__ sc2, const float* __restrict__ sh2,
              float* __restrict__ out)
{
  const int total = 26214400;
  for (int idx = blockIdx.x * 256 + threadIdx.x; idx < total; idx += gridDim.x * 256) {
    int n = idx / 819200, rem = idx - n * 819200;
    int ch = rem / 12800, tv = rem - ch * 12800;
    int b = ch >> 4, o = ch & 15;
    float val;
    if (b < 3) {
      val = sc2[b * 16 + o] * zbRaw[((b * 32 + n) * 16 + o) * 12800 + tv] + sh2[b * 16 + o];
    } else {
      int ko = 48 + o;
      val = sc1[ko] * preRaw[(n * 64 + ko) * 12800 + tv] + sh1[ko];
    }
    out[idx] = fmaxf(val + x[idx], 0.f);
  }
}

// ------------------------------------------------------------------
extern "C" void kernel_launch(void* const* d_in, const int* in_sizes, int n_in,
                              void* d_out, int out_size, void* d_ws, size_t ws_size,
                              hipStream_t stream)
{
  const float* x       = (const float*)d_in[0];
  const float* topo    = (const float*)d_in[1];
  const float* ln_g    = (const float*)d_in[2];
  const float* ln_b    = (const float*)d_in[3];
  const float* qk_w    = (const float*)d_in[4];
  const float* qk_b    = (const float*)d_in[5];
  const float* convd_w = (const float*)d_in[6];
  const float* convd_b = (const float*)d_in[7];
  const float* sagc_g  = (const float*)d_in[8];
  const float* sagc_b  = (const float*)d_in[9];
  const float* w1      = (const float*)d_in[10];
  const float* b1      = (const float*)d_in[11];
  const float* bn1_g   = (const float*)d_in[12];
  const float* bn1_b   = (const float*)d_in[13];
  const float* w2      = (const float*)d_in[14];
  const float* b2      = (const float*)d_in[15];
  const float* bn2_g   = (const float*)d_in[16];
  const float* bn2_b   = (const float*)d_in[17];
  float* out = (float*)d_out;
  float* ws  = (float*)d_ws;

  float* preRaw = ws;                    // 26,214,400
  float* zbRaw  = ws + 26214400;         // 19,660,800
  float* pSum1  = ws + 45875200;         // 1,048,576
  float* pSq1   = ws + 46923776;         // 1,048,576
  float* pSum2  = ws + 47972352;         // 49,152
  float* pSq2   = ws + 48021504;         // 49,152
  float* scS    = ws + 48070656;  float* shS = scS + 64;
  float* sc1    = scS + 128;      float* sh1 = scS + 192;
  float* sc2    = scS + 256;      float* sh2 = scS + 304;
  float* saRaw  = out;   // d_out doubles as sa scratch (dead before k7 writes)

  const float invN = 1.f / 409600.f;   // N*T*V

  k1_sa_sagc<<<dim3(512, 32), 256, 0, stream>>>(x, topo, ln_g, ln_b, qk_w, qk_b,
                                                convd_w, convd_b, saRaw, pSum1, pSq1);
  kreduce<<<64, 256, 0, stream>>>(pSum1, pSq1, 16384, invN, sagc_g, sagc_b, scS, shS);
  k3_ygc_pre<<<dim3(512, 32), 256, 0, stream>>>(x, saRaw, scS, shS, w1, b1,
                                                preRaw, pSum1, pSq1);
  kreduce<<<64, 256, 0, stream>>>(pSum1, pSq1, 16384, invN, bn1_g, bn1_b, sc1, sh1);
  k5_tcn_branch<<<dim3(32, 3, 32), 256, 0, stream>>>(preRaw, sc1, sh1, w2, b2,
                                                     zbRaw, pSum2, pSq2);
  kreduce<<<48, 256, 0, stream>>>(pSum2, pSq2, 1024, invN, bn2_g, bn2_b, sc2, sh2);
  k7_final<<<4096, 256, 0, stream>>>(x, preRaw, zbRaw, sc1, sh1, sc2, sh2, out);
}

// Round 2
// 663.704 us; speedup vs baseline: 2.0307x; 2.0307x over previous
//
#include <hip/hip_runtime.h>

// EncodingBlock — Round 2: k1 matmuls moved to bf16 MFMA (hi/lo split for QK).
// k3/k5/k7/kreduce unchanged from round 1.

#define EPS 1e-5f

typedef __bf16 bf16;
typedef __bf16 bf16x8 __attribute__((ext_vector_type(8)));
typedef float f32x4 __attribute__((ext_vector_type(4)));

// ------------------------------------------------------------------
// Prepack: qk_w -> hi/lo bf16 B-fragments; convd_w -> bf16 B-fragments.
// qkB: [hi 3072 | lo 3072] bf16, frag f = nt*2+ks (nt<3, ks<2), lane-major.
// convB: 12288 bf16, frag f = nt*6+ks (nt<4, ks<6), lane-major.
// ------------------------------------------------------------------
__global__ void kprepack(const float* __restrict__ qk_w, const float* __restrict__ convd_w,
                         bf16* __restrict__ qkB, bf16* __restrict__ convB)
{
  int gid = blockIdx.x * 256 + threadIdx.x;
  if (gid < 384) {                       // (nt,ks,lane) : 3*2*64
    int lane = gid & 63, f = gid >> 6;
    int nt = f >> 1, ks = f & 1;
    int row = nt * 16 + (lane & 15);     // output col m
    int col = ks * 32 + ((lane >> 4) * 8);
    const float* src = &qk_w[row * 64 + col];
    bf16* dh = &qkB[(f * 64 + lane) * 8];
    bf16* dl = dh + 3072;
    #pragma unroll
    for (int j = 0; j < 8; j++) {
      float w = src[j];
      bf16 h = (bf16)w;
      dh[j] = h;
      dl[j] = (bf16)(w - (float)h);
    }
  } else if (gid < 384 + 1536) {         // (nt,ks,lane) : 4*6*64
    int g = gid - 384;
    int lane = g & 63, f = g >> 6;
    int nt = f / 6, ks = f - nt * 6;
    int k0 = ks * 32 + ((lane >> 4) * 8);
    int h = k0 >> 6, c = k0 & 63;
    int o = nt * 16 + (lane & 15);
    const float* src = &convd_w[(h * 64 + o) * 64 + c];
    bf16* d = &convB[(f * 64 + lane) * 8];
    #pragma unroll
    for (int j = 0; j < 8; j++) d[j] = (bf16)src[j];
  }
}

// ------------------------------------------------------------------
// Kernel 1: fused SelfAttention + SA_GC (pre-BN), MFMA version.
// LDS 9828 floats = 39.3 KB -> 4 blocks/CU.
// ------------------------------------------------------------------
__global__ __launch_bounds__(256, 4)
void k1_sa_sagc(const float* __restrict__ x,
                const float* __restrict__ topo,
                const float* __restrict__ ln_g, const float* __restrict__ ln_b,
                const float* __restrict__ qk_b,
                const bf16* __restrict__ qkB, const bf16* __restrict__ convB,
                const float* __restrict__ convd_b,
                float* __restrict__ saRaw, float* __restrict__ pSum, float* __restrict__ pSq)
{
  const int t = blockIdx.x, n = blockIdx.y, tid = threadIdx.x;
  const int blk = n * 512 + t;
  const int lane = tid & 63, wave = tid >> 6;
  const int rr = lane & 15, co = (lane >> 4) * 8, rq = (lane >> 4) * 4;

  __shared__ __align__(16) float smem[9828];
  float* sFeat = smem;                      // [25][68] f32
  bf16*  featT = (bf16*)(smem + 1700);      // [64][40] bf16 (feat^T, cols j padded 0 at 25..31)
  float* sQK   = smem + 2980;               // [32][52] f32
  bf16*  sAttn = (bf16*)(smem + 4644);      // [3][32][40] bf16
  bf16*  zL    = (bf16*)(smem + 6564);      // [32][200] bf16
  float* sMu   = smem + 9764;               // [25]
  float* sRstd = smem + 9796;               // [25]
  float* sSa   = smem;                      // [64][29] overlay (sFeat/featT dead by then)

  // (1) load x tile -> sFeat[v][c] f32 and featT[c][j=v] bf16
  for (int idx = tid; idx < 1600; idx += 256) {
    int c = idx / 25, v = idx - c * 25;
    float f = x[((n * 64 + c) * 512 + t) * 25 + v];
    sFeat[v * 68 + c] = f;
    featT[c * 40 + v] = (bf16)f;
  }
  if (tid < 64) {
    #pragma unroll
    for (int j = 25; j < 32; j++) featT[tid * 40 + j] = (bf16)0.f;
  }
  __syncthreads();

  // (2) LayerNorm stats (8 lanes per row)
  {
    int r = tid >> 3, sub = tid & 7;
    if (r < 25) {
      float s = 0.f, q = 0.f;
      #pragma unroll
      for (int c = 0; c < 64; c += 8) { float f = sFeat[r * 68 + c + sub]; s += f; q += f * f; }
      s += __shfl_xor(s, 1); q += __shfl_xor(q, 1);
      s += __shfl_xor(s, 2); q += __shfl_xor(q, 2);
      s += __shfl_xor(s, 4); q += __shfl_xor(q, 4);
      if (sub == 0) {
        float mu = s * (1.f / 64.f);
        float var = q * (1.f / 64.f) - mu * mu;
        sMu[r] = mu; sRstd[r] = rsqrtf(var + EPS);
      }
    }
  }
  __syncthreads();

  // (3) QK projection via MFMA, hi/lo bf16 split. waves 0..2 own N-tiles of 48 cols.
  if (wave < 3) {
    const int nt = wave;
    bf16x8 Ah[2][2], Al[2][2];
    #pragma unroll
    for (int mt = 0; mt < 2; mt++) {
      int r0 = mt * 16 + rr;
      bool ok = r0 < 25;
      float mu = ok ? sMu[r0] : 0.f;
      float rs = ok ? sRstd[r0] : 0.f;
      #pragma unroll
      for (int ks = 0; ks < 2; ks++) {
        int c0 = ks * 32 + co;
        float4 fa, fb;
        if (ok) { fa = *(const float4*)&sFeat[r0 * 68 + c0];
                  fb = *(const float4*)&sFeat[r0 * 68 + c0 + 4]; }
        else    { fa = make_float4(0,0,0,0); fb = fa; }
        float4 g0  = *(const float4*)&ln_g[c0], g1  = *(const float4*)&ln_g[c0 + 4];
        float4 bb0 = *(const float4*)&ln_b[c0], bb1 = *(const float4*)&ln_b[c0 + 4];
        #define LNY(F, G, B) (ok ? ((F) - mu) * rs * (G) + (B) : 0.f)
        float y0 = LNY(fa.x, g0.x, bb0.x), y1 = LNY(fa.y, g0.y, bb0.y);
        float y2 = LNY(fa.z, g0.z, bb0.z), y3 = LNY(fa.w, g0.w, bb0.w);
        float y4 = LNY(fb.x, g1.x, bb1.x), y5 = LNY(fb.y, g1.y, bb1.y);
        float y6 = LNY(fb.z, g1.z, bb1.z), y7 = LNY(fb.w, g1.w, bb1.w);
        #undef LNY
        bf16 h0=(bf16)y0, h1=(bf16)y1, h2=(bf16)y2, h3=(bf16)y3;
        bf16 h4=(bf16)y4, h5=(bf16)y5, h6=(bf16)y6, h7=(bf16)y7;
        Ah[mt][ks] = (bf16x8){h0,h1,h2,h3,h4,h5,h6,h7};
        Al[mt][ks] = (bf16x8){(bf16)(y0-(float)h0),(bf16)(y1-(float)h1),
                              (bf16)(y2-(float)h2),(bf16)(y3-(float)h3),
                              (bf16)(y4-(float)h4),(bf16)(y5-(float)h5),
                              (bf16)(y6-(float)h6),(bf16)(y7-(float)h7)};
      }
    }
    float qb = qk_b[nt * 16 + rr];
    #pragma unroll
    for (int mt = 0; mt < 2; mt++) {
      f32x4 acc = {qb, qb, qb, qb};
      #pragma unroll
      for (int ks = 0; ks < 2; ks++) {
        bf16x8 Bh = *(const bf16x8*)&qkB[((nt * 2 + ks) * 64 + lane) * 8];
        bf16x8 Bl = *(const bf16x8*)&qkB[3072 + ((nt * 2 + ks) * 64 + lane) * 8];
        acc = __builtin_amdgcn_mfma_f32_16x16x32_bf16(Ah[mt][ks], Bh, acc, 0, 0, 0);
        acc = __builtin_amdgcn_mfma_f32_16x16x32_bf16(Ah[mt][ks], Bl, acc, 0, 0, 0);
        acc = __builtin_amdgcn_mfma_f32_16x16x32_bf16(Al[mt][ks], Bh, acc, 0, 0, 0);
      }
      #pragma unroll
      for (int r = 0; r < 4; r++)
        sQK[(mt * 16 + rq + r) * 52 + nt * 16 + rr] = acc[r];
    }
  }
  __syncthreads();

  // (4) dots + softmax + *topo -> sAttn bf16 (rows>=25 zeroed, cols 25..31 zeroed)
  if (tid < 96) {
    if (tid < 75) {
      int h = tid / 25, i = tid - (tid / 25) * 25;
      const float* qr = &sQK[i * 52 + h * 8];
      float4 qa = *(const float4*)qr, qb4 = *(const float4*)(qr + 4);
      float lgv[25];
      float lmax = -3.4e38f;
      #pragma unroll
      for (int j = 0; j < 25; j++) {
        const float* kr = &sQK[j * 52 + 24 + h * 8];
        float4 ka = *(const float4*)kr, kb = *(const float4*)(kr + 4);
        float d = qa.x * ka.x + qa.y * ka.y + qa.z * ka.z + qa.w * ka.w
                + qb4.x * kb.x + qb4.y * kb.y + qb4.z * kb.z + qb4.w * kb.w;
        d *= 0.35355339059327373f;   // 8^-0.5
        lgv[j] = d;
        lmax = fmaxf(lmax, d);
      }
      float se = 0.f;
      #pragma unroll
      for (int j = 0; j < 25; j++) { float e = __expf(lgv[j] - lmax); lgv[j] = e; se += e; }
      float inv = 1.f / se;
      bf16* ar = &sAttn[(h * 32 + i) * 40];
      #pragma unroll
      for (int j = 0; j < 25; j++) ar[j] = (bf16)(lgv[j] * inv * topo[(h * 25 + i) * 25 + j]);
      #pragma unroll
      for (int j = 25; j < 32; j++) ar[j] = (bf16)0.f;
    } else if (tid < 96 && tid - 75 < 21) {
      int k = tid - 75;
      int h = k / 7, i = 25 + (k - (k / 7) * 7);
      bf16* ar = &sAttn[(h * 32 + i) * 40];
      #pragma unroll
      for (int j = 0; j < 32; j++) ar[j] = (bf16)0.f;
    }
  }
  __syncthreads();

  // (5) z = A_h @ feat via MFMA. wave w owns feat-col tile w (16 cols).
  {
    const int nt = wave;
    bf16x8 Bf = *(const bf16x8*)&featT[(nt * 16 + rr) * 40 + co];
    #pragma unroll
    for (int h = 0; h < 3; h++) {
      #pragma unroll
      for (int mt = 0; mt < 2; mt++) {
        bf16x8 Af = *(const bf16x8*)&sAttn[(h * 32 + mt * 16 + rr) * 40 + co];
        f32x4 az = {0.f, 0.f, 0.f, 0.f};
        az = __builtin_amdgcn_mfma_f32_16x16x32_bf16(Af, Bf, az, 0, 0, 0);
        #pragma unroll
        for (int r = 0; r < 4; r++)
          zL[(mt * 16 + rq + r) * 200 + h * 64 + nt * 16 + rr] = (bf16)az[r];
      }
    }
  }
  __syncthreads();

  // (6) sa = z @ Wcat via MFMA. wave w owns output-col tile w (16 cols).
  {
    const int nt = wave;
    int o = nt * 16 + rr;
    float cb = convd_b[o] + convd_b[64 + o] + convd_b[128 + o];
    #pragma unroll
    for (int mt = 0; mt < 2; mt++) {
      f32x4 acc = {cb, cb, cb, cb};
      #pragma unroll
      for (int ks = 0; ks < 6; ks++) {
        bf16x8 Az = *(const bf16x8*)&zL[(mt * 16 + rr) * 200 + ks * 32 + co];
        bf16x8 Bw = *(const bf16x8*)&convB[((nt * 6 + ks) * 64 + lane) * 8];
        acc = __builtin_amdgcn_mfma_f32_16x16x32_bf16(Az, Bw, acc, 0, 0, 0);
      }
      #pragma unroll
      for (int r = 0; r < 4; r++) {
        int i = mt * 16 + rq + r;
        if (i < 25) sSa[o * 29 + i] = acc[r];
      }
    }
  }
  __syncthreads();

  // (7) store saRaw + BN partials
  for (int idx = tid; idx < 1600; idx += 256) {
    int o = idx / 25, i2 = idx - o * 25;
    saRaw[((n * 64 + o) * 512 + t) * 25 + i2] = sSa[o * 29 + i2];
  }
  if (tid < 64) {
    float s = 0.f, q = 0.f;
    #pragma unroll
    for (int i = 0; i < 25; i++) { float v = sSa[tid * 29 + i]; s += v; q += v * v; }
    pSum[tid * 16384 + blk] = s;
    pSq [tid * 16384 + blk] = q;
  }
}

// ------------------------------------------------------------------
// Generic BN-stat reduce: one block per channel
// ------------------------------------------------------------------
__global__ __launch_bounds__(256, 4)
void kreduce(const float* __restrict__ pS, const float* __restrict__ pQ, int npart, float invN,
             const float* __restrict__ g, const float* __restrict__ bta,
             float* __restrict__ sc, float* __restrict__ sh)
{
  int c = blockIdx.x, tid = threadIdx.x;
  float s = 0.f, q = 0.f;
  for (int i = tid; i < npart; i += 256) { s += pS[c * npart + i]; q += pQ[c * npart + i]; }
  #pragma unroll
  for (int m = 1; m < 64; m <<= 1) { s += __shfl_xor(s, m); q += __shfl_xor(q, m); }
  __shared__ float rs[4], rq[4];
  int w = tid >> 6;
  if ((tid & 63) == 0) { rs[w] = s; rq[w] = q; }
  __syncthreads();
  if (tid == 0) {
    float S = rs[0] + rs[1] + rs[2] + rs[3];
    float Q = rq[0] + rq[1] + rq[2] + rq[3];
    float mu = S * invN, var = Q * invN - mu * mu;
    float r = rsqrtf(var + EPS);
    sc[c] = g[c] * r;
    sh[c] = bta[c] - mu * g[c] * r;
  }
}

// ------------------------------------------------------------------
// Kernel 3: y_gc = relu(bn(sa)+x); pre = y_gc @ W1 + b1; partials for bn1
// ------------------------------------------------------------------
__global__ __launch_bounds__(256, 2)
void k3_ygc_pre(const float* __restrict__ x, const float* __restrict__ saRaw,
                const float* __restrict__ scS, const float* __restrict__ shS,
                const float* __restrict__ w1g, const float* __restrict__ b1,
                float* __restrict__ preRaw, float* __restrict__ pSum, float* __restrict__ pSq)
{
  const int t = blockIdx.x, n = blockIdx.y, tid = threadIdx.x;
  const int blk = n * 512 + t;
  __shared__ __align__(16) float sYgc[25 * 68];
  __shared__ __align__(16) float sW1[64 * 68];   // [c][ko]
  __shared__ float sPre[64 * 29];

  for (int idx = tid; idx < 1600; idx += 256) {
    int c = idx / 25, v = idx - c * 25;
    int a = ((n * 64 + c) * 512 + t) * 25 + v;
    float val = scS[c] * saRaw[a] + shS[c] + x[a];
    sYgc[v * 68 + c] = fmaxf(val, 0.f);
  }
  for (int idx = tid; idx < 4096; idx += 256) {
    int c = idx >> 6, ko = idx & 63;
    sW1[c * 68 + ko] = w1g[ko * 64 + c];
  }
  __syncthreads();

  int tx = tid & 15, o4 = tx * 4, ty = tid >> 4;
  float acc[2][4];
  { float4 bb = *(const float4*)&b1[o4];
    acc[0][0] = acc[1][0] = bb.x; acc[0][1] = acc[1][1] = bb.y;
    acc[0][2] = acc[1][2] = bb.z; acc[0][3] = acc[1][3] = bb.w; }
  for (int c0 = 0; c0 < 64; c0 += 4) {
    float4 w0  = *(const float4*)&sW1[(c0 + 0) * 68 + o4];
    float4 wv1 = *(const float4*)&sW1[(c0 + 1) * 68 + o4];
    float4 wv2 = *(const float4*)&sW1[(c0 + 2) * 68 + o4];
    float4 wv3 = *(const float4*)&sW1[(c0 + 3) * 68 + o4];
    #pragma unroll
    for (int r = 0; r < 2; r++) {
      int i = ty + 16 * r;
      if (i < 25) {
        float4 a4 = *(const float4*)&sYgc[i * 68 + c0];
        acc[r][0] += a4.x * w0.x + a4.y * wv1.x + a4.z * wv2.x + a4.w * wv3.x;
        acc[r][1] += a4.x * w0.y + a4.y * wv1.y + a4.z * wv2.y + a4.w * wv3.y;
        acc[r][2] += a4.x * w0.z + a4.y * wv1.z + a4.z * wv2.z + a4.w * wv3.z;
        acc[r][3] += a4.x * w0.w + a4.y * wv1.w + a4.z * wv2.w + a4.w * wv3.w;
      }
    }
  }
  #pragma unroll
  for (int r = 0; r < 2; r++) {
    int i = ty + 16 * r;
    if (i < 25) {
      #pragma unroll
      for (int j = 0; j < 4; j++) sPre[(o4 + j) * 29 + i] = acc[r][j];
    }
  }
  __syncthreads();
  for (int idx = tid; idx < 1600; idx += 256) {
    int ko = idx / 25, v = idx - ko * 25;
    preRaw[((n * 64 + ko) * 512 + t) * 25 + v] = sPre[ko * 29 + v];
  }
  if (tid < 64) {
    float s = 0.f, q = 0.f;
    #pragma unroll
    for (int i = 0; i < 25; i++) { float v = sPre[tid * 29 + i]; s += v; q += v * v; }
    pSum[tid * 16384 + blk] = s;
    pSq [tid * 16384 + blk] = q;
  }
}

// ------------------------------------------------------------------
// Kernel 5: TCN branches (dilated conv5 d=1,2 and maxpool3), + bn2 partials
// ------------------------------------------------------------------
template<int D>
__device__ __forceinline__ void conv5(const float* __restrict__ sIn, const float* __restrict__ sW,
                                      float4 bias, int o4, int v, int tb, float acc[8][4])
{
  #pragma unroll
  for (int s = 0; s < 8; s++) {
    acc[s][0] = bias.x; acc[s][1] = bias.y; acc[s][2] = bias.z; acc[s][3] = bias.w;
  }
  const int NW = 8 + 4 * D;
  for (int ic = 0; ic < 16; ic++) {
    float4 wk[5];
    #pragma unroll
    for (int kt = 0; kt < 5; kt++) wk[kt] = *(const float4*)&sW[(ic * 5 + kt) * 16 + o4];
    float xw[8 + 4 * D];
    #pragma unroll
    for (int w = 0; w < NW; w++) xw[w] = sIn[(ic * 24 + (tb - 2 * D + w + 4)) * 25 + v];
    #pragma unroll
    for (int s = 0; s < 8; s++)
      #pragma unroll
      for (int kt = 0; kt < 5; kt++) {
        float xv = xw[s + kt * D];
        acc[s][0] += xv * wk[kt].x; acc[s][1] += xv * wk[kt].y;
        acc[s][2] += xv * wk[kt].z; acc[s][3] += xv * wk[kt].w;
      }
  }
}

__global__ __launch_bounds__(256, 2)
void k5_tcn_branch(const float* __restrict__ preRaw,
                   const float* __restrict__ sc1, const float* __restrict__ sh1,
                   const float* __restrict__ w2, const float* __restrict__ b2,
                   float* __restrict__ zbRaw, float* __restrict__ pSum2, float* __restrict__ pSq2)
{
  const int tt = blockIdx.x, b = blockIdx.y, n = blockIdx.z;
  const int tid = threadIdx.x, t0 = tt * 16;
  __shared__ __align__(16) float sIn[16 * 24 * 25];
  __shared__ __align__(16) float sW[16 * 5 * 16];
  __shared__ float sRedS[4][4][4], sRedQ[4][4][4];

  for (int idx = tid; idx < 9600; idx += 256) {
    int ic = idx / 600, rr = idx - ic * 600;
    int r = rr / 25, v = rr - r * 25;
    int gt = t0 - 4 + r, ch = b * 16 + ic;
    float val = 0.f;
    if (gt >= 0 && gt < 512)
      val = fmaxf(sc1[ch] * preRaw[((n * 64 + ch) * 512 + gt) * 25 + v] + sh1[ch], 0.f);
    sIn[(ic * 24 + r) * 25 + v] = val;
  }
  if (b < 2)
    for (int idx = tid; idx < 1280; idx += 256) {
      int o = idx / 80, rem = idx - o * 80;
      int ic = rem / 5, kt = rem - ic * 5;
      sW[(ic * 5 + kt) * 16 + o] = w2[((b * 16 + o) * 16 + ic) * 5 + kt];
    }
  __syncthreads();

  float po[4] = {0.f, 0.f, 0.f, 0.f}, pq[4] = {0.f, 0.f, 0.f, 0.f};
  if (tid < 200) {
    int tx = tid & 3, o4 = tx * 4;
    int g = tid >> 2;
    int v = g % 25, th = g / 25;
    int tb = th * 8;
    float acc[8][4];
    if (b == 0)      conv5<1>(sIn, sW, *(const float4*)&b2[o4],      o4, v, tb, acc);
    else if (b == 1) conv5<2>(sIn, sW, *(const float4*)&b2[16 + o4], o4, v, tb, acc);
    else {
      #pragma unroll
      for (int s = 0; s < 8; s++)
        #pragma unroll
        for (int j = 0; j < 4; j++) {
          int o = o4 + j, r = tb + s + 4;
          float a = sIn[(o * 24 + r - 1) * 25 + v];
          float m = sIn[(o * 24 + r    ) * 25 + v];
          float c = sIn[(o * 24 + r + 1) * 25 + v];
          acc[s][j] = fmaxf(fmaxf(a, m), c);
        }
    }
    #pragma unroll
    for (int s = 0; s < 8; s++) {
      int gt = t0 + tb + s;
      #pragma unroll
      for (int j = 0; j < 4; j++) {
        float val = acc[s][j];
        zbRaw[(((b * 32 + n) * 16 + (o4 + j)) * 512 + gt) * 25 + v] = val;
        po[j] += val; pq[j] += val * val;
      }
    }
  }
  #pragma unroll
  for (int m = 4; m < 64; m <<= 1) {
    #pragma unroll
    for (int j = 0; j < 4; j++) { po[j] += __shfl_xor(po[j], m); pq[j] += __shfl_xor(pq[j], m); }
  }
  int lane = tid & 63, w = tid >> 6;
  if (lane < 4) {
    #pragma unroll
    for (int j = 0; j < 4; j++) { sRedS[w][lane][j] = po[j]; sRedQ[w][lane][j] = pq[j]; }
  }
  __syncthreads();
  if (tid < 16) {
    int o = tid, txo = o >> 2, j = o & 3;
    float s = 0.f, q = 0.f;
    #pragma unroll
    for (int ww = 0; ww < 4; ww++) { s += sRedS[ww][txo][j]; q += sRedQ[ww][txo][j]; }
    int pidx = (b * 16 + o) * 1024 + (n * 32 + tt);
    pSum2[pidx] = s; pSq2[pidx] = q;
  }
}

// ------------------------------------------------------------------
// Kernel 7: concat branches + bn + residual + relu
// ------------------------------------------------------------------
__global__ __launch_bounds__(256, 4)
void k7_final(const float* __restrict__ x, const float* __restrict__ preRaw,
              const float* __restrict__ zbRaw,
              const float* __restrict__ sc1, const float* __restrict__ sh1,
              const float* __restrict__ sc2, const float* __restrict__ sh2,
              float* __restrict__ out)
{
  const int total = 26214400;
  for (int idx = blockIdx.x * 256 + threadIdx.x; idx < total; idx += gridDim.x * 256) {
    int n = idx / 819200, rem = idx - n * 819200;
    int ch = rem / 12800, tv = rem - ch * 12800;
    int b = ch >> 4, o = ch & 15;
    float val;
    if (b < 3) {
      val = sc2[b * 16 + o] * zbRaw[((b * 32 + n) * 16 + o) * 12800 + tv] + sh2[b * 16 + o];
    } else {
      int ko = 48 + o;
      val = sc1[ko] * preRaw[(n * 64 + ko) * 12800 + tv] + sh1[ko];
    }
    out[idx] = fmaxf(val + x[idx], 0.f);
  }
}

// ------------------------------------------------------------------
extern "C" void kernel_launch(void* const* d_in, const int* in_sizes, int n_in,
                              void* d_out, int out_size, void* d_ws, size_t ws_size,
                              hipStream_t stream)
{
  const float* x       = (const float*)d_in[0];
  const float* topo    = (const float*)d_in[1];
  const float* ln_g    = (const float*)d_in[2];
  const float* ln_b    = (const float*)d_in[3];
  const float* qk_w    = (const float*)d_in[4];
  const float* qk_b    = (const float*)d_in[5];
  const float* convd_w = (const float*)d_in[6];
  const float* convd_b = (const float*)d_in[7];
  const float* sagc_g  = (const float*)d_in[8];
  const float* sagc_b  = (const float*)d_in[9];
  const float* w1      = (const float*)d_in[10];
  const float* b1      = (const float*)d_in[11];
  const float* bn1_g   = (const float*)d_in[12];
  const float* bn1_b   = (const float*)d_in[13];
  const float* w2      = (const float*)d_in[14];
  const float* b2      = (const float*)d_in[15];
  const float* bn2_g   = (const float*)d_in[16];
  const float* bn2_b   = (const float*)d_in[17];
  float* out = (float*)d_out;
  float* ws  = (float*)d_ws;

  float* preRaw = ws;                    // 26,214,400
  float* zbRaw  = ws + 26214400;         // 19,660,800 (also hosts prepacked frags pre-k5)
  float* pSum1  = ws + 45875200;         // 1,048,576
  float* pSq1   = ws + 46923776;         // 1,048,576
  float* pSum2  = ws + 47972352;         // 49,152
  float* pSq2   = ws + 48021504;         // 49,152
  float* scS    = ws + 48070656;  float* shS = scS + 64;
  float* sc1    = scS + 128;      float* sh1 = scS + 192;
  float* sc2    = scS + 256;      float* sh2 = scS + 304;
  float* saRaw  = out;   // d_out doubles as sa scratch (dead before k7 writes)

  // prepacked weight fragments live in the (not-yet-written) zbRaw region:
  bf16* qkB   = (bf16*)(ws + 26214400);          // 6144 bf16 (hi 3072 | lo 3072)
  bf16* convB = (bf16*)(ws + 26214400 + 3072);   // 12288 bf16

  const float invN = 1.f / 409600.f;   // N*T*V

  kprepack<<<8, 256, 0, stream>>>(qk_w, convd_w, qkB, convB);
  k1_sa_sagc<<<dim3(512, 32), 256, 0, stream>>>(x, topo, ln_g, ln_b, qk_b,
                                                qkB, convB, convd_b, saRaw, pSum1, pSq1);
  kreduce<<<64, 256, 0, stream>>>(pSum1, pSq1, 16384, invN, sagc_g, sagc_b, scS, shS);
  k3_ygc_pre<<<dim3(512, 32), 256, 0, stream>>>(x, saRaw, scS, shS, w1, b1,
                                                preRaw, pSum1, pSq1);
  kreduce<<<64, 256, 0, stream>>>(pSum1, pSq1, 16384, invN, bn1_g, bn1_b, sc1, sh1);
  k5_tcn_branch<<<dim3(32, 3, 32), 256, 0, stream>>>(preRaw, sc1, sh1, w2, b2,
                                                     zbRaw, pSum2, pSq2);
  kreduce<<<48, 256, 0, stream>>>(pSum2, pSq2, 1024, invN, bn2_g, bn2_b, sc2, sh2);
  k7_final<<<4096, 256, 0, stream>>>(x, preRaw, zbRaw, sc1, sh1, sc2, sh2, out);
}

// Round 3
// 532.280 us; speedup vs baseline: 2.5321x; 1.2469x over previous
//
#include <hip/hip_runtime.h>

// EncodingBlock — Round 3:
//  * k3 converted to MFMA (hi/lo bf16 A, hi/lo w1 B-frags prepacked)
//  * saRaw/preRaw/zbRaw stored as bf16 (pre-BN values; stats stay f32)
//  * k1 LDS overlays: 39.4 KB -> 25.9 KB (6 blocks/CU)
//  * BN partials written coalesced [blk][c]; kreduce reads strided (L2)

#define EPS 1e-5f

typedef __bf16 bf16;
typedef __bf16 bf16x8 __attribute__((ext_vector_type(8)));
typedef __bf16 bf16x2 __attribute__((ext_vector_type(2)));
typedef float f32x4 __attribute__((ext_vector_type(4)));

// ------------------------------------------------------------------
// Prepack weights to MFMA B-fragments.
// qkB: [hi 3072 | lo 3072] bf16 (f = nt*2+ks, nt<3, ks<2)
// convB: 12288 bf16 (f = nt*6+ks, nt<4, ks<6)
// w1B: [hi 4096 | lo 4096] bf16 (f = nt*2+ks, nt<4, ks<2)
// ------------------------------------------------------------------
__global__ void kprepack(const float* __restrict__ qk_w, const float* __restrict__ convd_w,
                         const float* __restrict__ w1g,
                         bf16* __restrict__ qkB, bf16* __restrict__ convB, bf16* __restrict__ w1B)
{
  int gid = blockIdx.x * 256 + threadIdx.x;
  if (gid < 384) {                       // qk: (nt,ks,lane) 3*2*64
    int lane = gid & 63, f = gid >> 6;
    int nt = f >> 1, ks = f & 1;
    int row = nt * 16 + (lane & 15);
    int col = ks * 32 + ((lane >> 4) * 8);
    const float* src = &qk_w[row * 64 + col];
    bf16* dh = &qkB[(f * 64 + lane) * 8];
    bf16* dl = dh + 3072;
    #pragma unroll
    for (int j = 0; j < 8; j++) {
      float w = src[j];
      bf16 h = (bf16)w;
      dh[j] = h;
      dl[j] = (bf16)(w - (float)h);
    }
  } else if (gid < 1920) {               // convd: (nt,ks,lane) 4*6*64
    int g = gid - 384;
    int lane = g & 63, f = g >> 6;
    int nt = f / 6, ks = f - nt * 6;
    int k0 = ks * 32 + ((lane >> 4) * 8);
    int h = k0 >> 6, c = k0 & 63;
    int o = nt * 16 + (lane & 15);
    const float* src = &convd_w[(h * 64 + o) * 64 + c];
    bf16* d = &convB[(f * 64 + lane) * 8];
    #pragma unroll
    for (int j = 0; j < 8; j++) d[j] = (bf16)src[j];
  } else if (gid < 2432) {               // w1: (nt,ks,lane) 4*2*64, hi/lo
    int g = gid - 1920;
    int lane = g & 63, f = g >> 6;
    int nt = f >> 1, ks = f & 1;
    int ko = nt * 16 + (lane & 15);
    int c0 = ks * 32 + ((lane >> 4) * 8);
    const float* src = &w1g[ko * 64 + c0];
    bf16* dh = &w1B[(f * 64 + lane) * 8];
    bf16* dl = dh + 4096;
    #pragma unroll
    for (int j = 0; j < 8; j++) {
      float w = src[j];
      bf16 h = (bf16)w;
      dh[j] = h;
      dl[j] = (bf16)(w - (float)h);
    }
  }
}

// ------------------------------------------------------------------
// Kernel 1: fused SelfAttention + SA_GC (pre-BN), MFMA.
// LDS 6464 floats = 25.9 KB -> 6 blocks/CU.
// ------------------------------------------------------------------
__global__ __launch_bounds__(256, 6)
void k1_sa_sagc(const float* __restrict__ x,
                const float* __restrict__ topo,
                const float* __restrict__ ln_g, const float* __restrict__ ln_b,
                const float* __restrict__ qk_b,
                const bf16* __restrict__ qkB, const bf16* __restrict__ convB,
                const float* __restrict__ convd_b,
                bf16* __restrict__ saB, float* __restrict__ pSum, float* __restrict__ pSq)
{
  const int t = blockIdx.x, n = blockIdx.y, tid = threadIdx.x;
  const int blk = n * 512 + t;
  const int lane = tid & 63, wave = tid >> 6;
  const int rr = lane & 15, co = (lane >> 4) * 8, rq = (lane >> 4) * 4;

  __shared__ __align__(16) float smem[6464];
  bf16*  featT = (bf16*)smem;               // [64][40] bf16   [0..1280)
  bf16*  sAttn = (bf16*)(smem + 1280);      // [3][32][40]     [1280..3200)
  float* sFeat = smem + 3200;               // [25][68] f32    [3200..4900)
  float* sQK   = smem + 4900;               // [32][52] f32    [4900..6564)->6564? fits 4900+1664=6564? no: 6564>6464
  bf16*  zL    = (bf16*)(smem + 3200);      // [32][200] bf16  [3200..6400) overlay (sFeat,sQK dead)
  float* sMu   = smem + 6400;
  float* sRstd = smem + 6432;
  float* sSa   = smem;                      // [64][29] overlay (featT/sAttn dead)

  // (1) load x tile -> sFeat[v][c] f32 and featT[c][j=v] bf16
  for (int idx = tid; idx < 1600; idx += 256) {
    int c = idx / 25, v = idx - c * 25;
    float f = x[((n * 64 + c) * 512 + t) * 25 + v];
    sFeat[v * 68 + c] = f;
    featT[c * 40 + v] = (bf16)f;
  }
  if (tid < 64) {
    #pragma unroll
    for (int j = 25; j < 32; j++) featT[tid * 40 + j] = (bf16)0.f;
  }
  __syncthreads();

  // (2) LayerNorm stats
  {
    int r = tid >> 3, sub = tid & 7;
    if (r < 25) {
      float s = 0.f, q = 0.f;
      #pragma unroll
      for (int c = 0; c < 64; c += 8) { float f = sFeat[r * 68 + c + sub]; s += f; q += f * f; }
      s += __shfl_xor(s, 1); q += __shfl_xor(q, 1);
      s += __shfl_xor(s, 2); q += __shfl_xor(q, 2);
      s += __shfl_xor(s, 4); q += __shfl_xor(q, 4);
      if (sub == 0) {
        float mu = s * (1.f / 64.f);
        float var = q * (1.f / 64.f) - mu * mu;
        sMu[r] = mu; sRstd[r] = rsqrtf(var + EPS);
      }
    }
  }
  __syncthreads();

  // (3) QK projection via MFMA (hi/lo split)
  if (wave < 3) {
    const int nt = wave;
    bf16x8 Ah[2][2], Al[2][2];
    #pragma unroll
    for (int mt = 0; mt < 2; mt++) {
      int r0 = mt * 16 + rr;
      bool ok = r0 < 25;
      float mu = ok ? sMu[r0] : 0.f;
      float rs = ok ? sRstd[r0] : 0.f;
      #pragma unroll
      for (int ks = 0; ks < 2; ks++) {
        int c0 = ks * 32 + co;
        float4 fa, fb;
        if (ok) { fa = *(const float4*)&sFeat[r0 * 68 + c0];
                  fb = *(const float4*)&sFeat[r0 * 68 + c0 + 4]; }
        else    { fa = make_float4(0,0,0,0); fb = fa; }
        float4 g0  = *(const float4*)&ln_g[c0], g1  = *(const float4*)&ln_g[c0 + 4];
        float4 bb0 = *(const float4*)&ln_b[c0], bb1 = *(const float4*)&ln_b[c0 + 4];
        float y[8];
        y[0] = ok ? (fa.x - mu) * rs * g0.x + bb0.x : 0.f;
        y[1] = ok ? (fa.y - mu) * rs * g0.y + bb0.y : 0.f;
        y[2] = ok ? (fa.z - mu) * rs * g0.z + bb0.z : 0.f;
        y[3] = ok ? (fa.w - mu) * rs * g0.w + bb0.w : 0.f;
        y[4] = ok ? (fb.x - mu) * rs * g1.x + bb1.x : 0.f;
        y[5] = ok ? (fb.y - mu) * rs * g1.y + bb1.y : 0.f;
        y[6] = ok ? (fb.z - mu) * rs * g1.z + bb1.z : 0.f;
        y[7] = ok ? (fb.w - mu) * rs * g1.w + bb1.w : 0.f;
        #pragma unroll
        for (int j = 0; j < 8; j++) {
          bf16 h = (bf16)y[j];
          Ah[mt][ks][j] = h;
          Al[mt][ks][j] = (bf16)(y[j] - (float)h);
        }
      }
    }
    float qb = qk_b[nt * 16 + rr];
    #pragma unroll
    for (int mt = 0; mt < 2; mt++) {
      f32x4 acc = {qb, qb, qb, qb};
      #pragma unroll
      for (int ks = 0; ks < 2; ks++) {
        bf16x8 Bh = *(const bf16x8*)&qkB[((nt * 2 + ks) * 64 + lane) * 8];
        bf16x8 Bl = *(const bf16x8*)&qkB[3072 + ((nt * 2 + ks) * 64 + lane) * 8];
        acc = __builtin_amdgcn_mfma_f32_16x16x32_bf16(Ah[mt][ks], Bh, acc, 0, 0, 0);
        acc = __builtin_amdgcn_mfma_f32_16x16x32_bf16(Ah[mt][ks], Bl, acc, 0, 0, 0);
        acc = __builtin_amdgcn_mfma_f32_16x16x32_bf16(Al[mt][ks], Bh, acc, 0, 0, 0);
      }
      #pragma unroll
      for (int r = 0; r < 4; r++)
        sQK[(mt * 16 + rq + r) * 52 + nt * 16 + rr] = acc[r];
    }
  }
  __syncthreads();

  // (4) dots + softmax + *topo -> sAttn bf16 (pad rows/cols zeroed)
  if (tid < 96) {
    if (tid < 75) {
      int h = tid / 25, i = tid - (tid / 25) * 25;
      const float* qr = &sQK[i * 52 + h * 8];
      float4 qa = *(const float4*)qr, qb4 = *(const float4*)(qr + 4);
      float lgv[25];
      float lmax = -3.4e38f;
      #pragma unroll
      for (int j = 0; j < 25; j++) {
        const float* kr = &sQK[j * 52 + 24 + h * 8];
        float4 ka = *(const float4*)kr, kb = *(const float4*)(kr + 4);
        float d = qa.x * ka.x + qa.y * ka.y + qa.z * ka.z + qa.w * ka.w
                + qb4.x * kb.x + qb4.y * kb.y + qb4.z * kb.z + qb4.w * kb.w;
        d *= 0.35355339059327373f;
        lgv[j] = d;
        lmax = fmaxf(lmax, d);
      }
      float se = 0.f;
      #pragma unroll
      for (int j = 0; j < 25; j++) { float e = __expf(lgv[j] - lmax); lgv[j] = e; se += e; }
      float inv = 1.f / se;
      bf16* ar = &sAttn[(h * 32 + i) * 40];
      #pragma unroll
      for (int j = 0; j < 25; j++) ar[j] = (bf16)(lgv[j] * inv * topo[(h * 25 + i) * 25 + j]);
      #pragma unroll
      for (int j = 25; j < 32; j++) ar[j] = (bf16)0.f;
    } else if (tid - 75 < 21) {
      int k = tid - 75;
      int h = k / 7, i = 25 + (k - (k / 7) * 7);
      bf16* ar = &sAttn[(h * 32 + i) * 40];
      #pragma unroll
      for (int j = 0; j < 32; j++) ar[j] = (bf16)0.f;
    }
  }
  __syncthreads();

  // (5) z = A_h @ feat via MFMA; wave owns 16 feat-cols
  {
    const int nt = wave;
    bf16x8 Bf = *(const bf16x8*)&featT[(nt * 16 + rr) * 40 + co];
    #pragma unroll
    for (int h = 0; h < 3; h++) {
      #pragma unroll
      for (int mt = 0; mt < 2; mt++) {
        bf16x8 Af = *(const bf16x8*)&sAttn[(h * 32 + mt * 16 + rr) * 40 + co];
        f32x4 az = {0.f, 0.f, 0.f, 0.f};
        az = __builtin_amdgcn_mfma_f32_16x16x32_bf16(Af, Bf, az, 0, 0, 0);
        #pragma unroll
        for (int r = 0; r < 4; r++)
          zL[(mt * 16 + rq + r) * 200 + h * 64 + nt * 16 + rr] = (bf16)az[r];
      }
    }
  }
  __syncthreads();

  // (6) sa = z @ Wcat via MFMA; wave owns 16 output cols
  {
    const int nt = wave;
    int o = nt * 16 + rr;
    float cb = convd_b[o] + convd_b[64 + o] + convd_b[128 + o];
    #pragma unroll
    for (int mt = 0; mt < 2; mt++) {
      f32x4 acc = {cb, cb, cb, cb};
      #pragma unroll
      for (int ks = 0; ks < 6; ks++) {
        bf16x8 Az = *(const bf16x8*)&zL[(mt * 16 + rr) * 200 + ks * 32 + co];
        bf16x8 Bw = *(const bf16x8*)&convB[((nt * 6 + ks) * 64 + lane) * 8];
        acc = __builtin_amdgcn_mfma_f32_16x16x32_bf16(Az, Bw, acc, 0, 0, 0);
      }
      #pragma unroll
      for (int r = 0; r < 4; r++) {
        int i = mt * 16 + rq + r;
        if (i < 25) sSa[o * 29 + i] = acc[r];
      }
    }
  }
  __syncthreads();

  // (7) store saRaw bf16 + BN partials (coalesced [blk][c])
  for (int idx = tid; idx < 1600; idx += 256) {
    int o = idx / 25, i2 = idx - o * 25;
    saB[((n * 64 + o) * 512 + t) * 25 + i2] = (bf16)sSa[o * 29 + i2];
  }
  if (tid < 64) {
    float s = 0.f, q = 0.f;
    #pragma unroll
    for (int i = 0; i < 25; i++) { float v = sSa[tid * 29 + i]; s += v; q += v * v; }
    pSum[blk * 64 + tid] = s;
    pSq [blk * 64 + tid] = q;
  }
}

// ------------------------------------------------------------------
// BN-stat reduce: one block per channel; partials layout [part][C]
// ------------------------------------------------------------------
__global__ __launch_bounds__(256, 4)
void kreduce(const float* __restrict__ pS, const float* __restrict__ pQ,
             int npart, int C, float invN,
             const float* __restrict__ g, const float* __restrict__ bta,
             float* __restrict__ sc, float* __restrict__ sh)
{
  int c = blockIdx.x, tid = threadIdx.x;
  float s = 0.f, q = 0.f;
  for (int i = tid; i < npart; i += 256) { s += pS[i * C + c]; q += pQ[i * C + c]; }
  #pragma unroll
  for (int m = 1; m < 64; m <<= 1) { s += __shfl_xor(s, m); q += __shfl_xor(q, m); }
  __shared__ float rs[4], rq[4];
  int w = tid >> 6;
  if ((tid & 63) == 0) { rs[w] = s; rq[w] = q; }
  __syncthreads();
  if (tid == 0) {
    float S = rs[0] + rs[1] + rs[2] + rs[3];
    float Q = rq[0] + rq[1] + rq[2] + rq[3];
    float mu = S * invN, var = Q * invN - mu * mu;
    float r = rsqrtf(var + EPS);
    sc[c] = g[c] * r;
    sh[c] = bta[c] - mu * g[c] * r;
  }
}

// ------------------------------------------------------------------
// Kernel 3: y_gc = relu(bn(sa)+x); pre = y_gc @ W1 + b1 via MFMA (hi/lo)
// LDS 3556 floats = 14.2 KB.
// ------------------------------------------------------------------
__global__ __launch_bounds__(256, 8)
void k3_ygc_pre(const float* __restrict__ x, const bf16* __restrict__ saB,
                const float* __restrict__ scS, const float* __restrict__ shS,
                const bf16* __restrict__ w1B, const float* __restrict__ b1,
                bf16* __restrict__ preB, float* __restrict__ pSum, float* __restrict__ pSq)
{
  const int t = blockIdx.x, n = blockIdx.y, tid = threadIdx.x;
  const int blk = n * 512 + t;
  const int lane = tid & 63, wave = tid >> 6;
  const int rr = lane & 15, co = (lane >> 4) * 8, rq = (lane >> 4) * 4;

  __shared__ __align__(16) float sYgc[25 * 68];
  __shared__ float sPre[64 * 29];

  for (int idx = tid; idx < 1600; idx += 256) {
    int c = idx / 25, v = idx - c * 25;
    int a = ((n * 64 + c) * 512 + t) * 25 + v;
    float val = scS[c] * (float)saB[a] + shS[c] + x[a];
    sYgc[v * 68 + c] = fmaxf(val, 0.f);
  }
  __syncthreads();

  {
    const int nt = wave;  // 0..3, output cols nt*16..+15
    bf16x8 Ah[2][2], Al[2][2];
    #pragma unroll
    for (int mt = 0; mt < 2; mt++) {
      int r0 = mt * 16 + rr;
      bool ok = r0 < 25;
      #pragma unroll
      for (int ks = 0; ks < 2; ks++) {
        float v[8];
        if (ok) {
          float4 fa = *(const float4*)&sYgc[r0 * 68 + ks * 32 + co];
          float4 fb = *(const float4*)&sYgc[r0 * 68 + ks * 32 + co + 4];
          v[0]=fa.x; v[1]=fa.y; v[2]=fa.z; v[3]=fa.w;
          v[4]=fb.x; v[5]=fb.y; v[6]=fb.z; v[7]=fb.w;
        } else {
          #pragma unroll
          for (int j = 0; j < 8; j++) v[j] = 0.f;
        }
        #pragma unroll
        for (int j = 0; j < 8; j++) {
          bf16 h = (bf16)v[j];
          Ah[mt][ks][j] = h;
          Al[mt][ks][j] = (bf16)(v[j] - (float)h);
        }
      }
    }
    float bb = b1[nt * 16 + rr];
    #pragma unroll
    for (int mt = 0; mt < 2; mt++) {
      f32x4 acc = {bb, bb, bb, bb};
      #pragma unroll
      for (int ks = 0; ks < 2; ks++) {
        bf16x8 Bh = *(const bf16x8*)&w1B[((nt * 2 + ks) * 64 + lane) * 8];
        bf16x8 Bl = *(const bf16x8*)&w1B[4096 + ((nt * 2 + ks) * 64 + lane) * 8];
        acc = __builtin_amdgcn_mfma_f32_16x16x32_bf16(Ah[mt][ks], Bh, acc, 0, 0, 0);
        acc = __builtin_amdgcn_mfma_f32_16x16x32_bf16(Ah[mt][ks], Bl, acc, 0, 0, 0);
        acc = __builtin_amdgcn_mfma_f32_16x16x32_bf16(Al[mt][ks], Bh, acc, 0, 0, 0);
      }
      #pragma unroll
      for (int r = 0; r < 4; r++) {
        int i = mt * 16 + rq + r;
        if (i < 25) sPre[(nt * 16 + rr) * 29 + i] = acc[r];
      }
    }
  }
  __syncthreads();

  for (int idx = tid; idx < 1600; idx += 256) {
    int ko = idx / 25, v = idx - ko * 25;
    preB[((n * 64 + ko) * 512 + t) * 25 + v] = (bf16)sPre[ko * 29 + v];
  }
  if (tid < 64) {
    float s = 0.f, q = 0.f;
    #pragma unroll
    for (int i = 0; i < 25; i++) { float v = sPre[tid * 29 + i]; s += v; q += v * v; }
    pSum[blk * 64 + tid] = s;
    pSq [blk * 64 + tid] = q;
  }
}

// ------------------------------------------------------------------
// Kernel 5: TCN branches (dilated conv5 d=1,2 and maxpool3) + bn2 partials
// ------------------------------------------------------------------
template<int D>
__device__ __forceinline__ void conv5(const float* __restrict__ sIn, const float* __restrict__ sW,
                                      float4 bias, int o4, int v, int tb, float acc[8][4])
{
  #pragma unroll
  for (int s = 0; s < 8; s++) {
    acc[s][0] = bias.x; acc[s][1] = bias.y; acc[s][2] = bias.z; acc[s][3] = bias.w;
  }
  const int NW = 8 + 4 * D;
  for (int ic = 0; ic < 16; ic++) {
    float4 wk[5];
    #pragma unroll
    for (int kt = 0; kt < 5; kt++) wk[kt] = *(const float4*)&sW[(ic * 5 + kt) * 16 + o4];
    float xw[8 + 4 * D];
    #pragma unroll
    for (int w = 0; w < NW; w++) xw[w] = sIn[(ic * 24 + (tb - 2 * D + w + 4)) * 25 + v];
    #pragma unroll
    for (int s = 0; s < 8; s++)
      #pragma unroll
      for (int kt = 0; kt < 5; kt++) {
        float xv = xw[s + kt * D];
        acc[s][0] += xv * wk[kt].x; acc[s][1] += xv * wk[kt].y;
        acc[s][2] += xv * wk[kt].z; acc[s][3] += xv * wk[kt].w;
      }
  }
}

__global__ __launch_bounds__(256, 2)
void k5_tcn_branch(const bf16* __restrict__ preB,
                   const float* __restrict__ sc1, const float* __restrict__ sh1,
                   const float* __restrict__ w2, const float* __restrict__ b2,
                   bf16* __restrict__ zbB, float* __restrict__ pSum2, float* __restrict__ pSq2)
{
  const int tt = blockIdx.x, b = blockIdx.y, n = blockIdx.z;
  const int tid = threadIdx.x, t0 = tt * 16;
  __shared__ __align__(16) float sIn[16 * 24 * 25];
  __shared__ __align__(16) float sW[16 * 5 * 16];
  __shared__ float sRedS[4][4][4], sRedQ[4][4][4];

  for (int idx = tid; idx < 9600; idx += 256) {
    int ic = idx / 600, rr = idx - ic * 600;
    int r = rr / 25, v = rr - r * 25;
    int gt = t0 - 4 + r, ch = b * 16 + ic;
    float val = 0.f;
    if (gt >= 0 && gt < 512)
      val = fmaxf(sc1[ch] * (float)preB[((n * 64 + ch) * 512 + gt) * 25 + v] + sh1[ch], 0.f);
    sIn[(ic * 24 + r) * 25 + v] = val;
  }
  if (b < 2)
    for (int idx = tid; idx < 1280; idx += 256) {
      int o = idx / 80, rem = idx - o * 80;
      int ic = rem / 5, kt = rem - ic * 5;
      sW[(ic * 5 + kt) * 16 + o] = w2[((b * 16 + o) * 16 + ic) * 5 + kt];
    }
  __syncthreads();

  float po[4] = {0.f, 0.f, 0.f, 0.f}, pq[4] = {0.f, 0.f, 0.f, 0.f};
  if (tid < 200) {
    int tx = tid & 3, o4 = tx * 4;
    int g = tid >> 2;
    int v = g % 25, th = g / 25;
    int tb = th * 8;
    float acc[8][4];
    if (b == 0)      conv5<1>(sIn, sW, *(const float4*)&b2[o4],      o4, v, tb, acc);
    else if (b == 1) conv5<2>(sIn, sW, *(const float4*)&b2[16 + o4], o4, v, tb, acc);
    else {
      #pragma unroll
      for (int s = 0; s < 8; s++)
        #pragma unroll
        for (int j = 0; j < 4; j++) {
          int o = o4 + j, r = tb + s + 4;
          float a = sIn[(o * 24 + r - 1) * 25 + v];
          float m = sIn[(o * 24 + r    ) * 25 + v];
          float c = sIn[(o * 24 + r + 1) * 25 + v];
          acc[s][j] = fmaxf(fmaxf(a, m), c);
        }
    }
    #pragma unroll
    for (int s = 0; s < 8; s++) {
      int gt = t0 + tb + s;
      #pragma unroll
      for (int j = 0; j < 4; j++) {
        float val = acc[s][j];
        zbB[(((b * 32 + n) * 16 + (o4 + j)) * 512 + gt) * 25 + v] = (bf16)val;
        po[j] += val; pq[j] += val * val;
      }
    }
  }
  #pragma unroll
  for (int m = 4; m < 64; m <<= 1) {
    #pragma unroll
    for (int j = 0; j < 4; j++) { po[j] += __shfl_xor(po[j], m); pq[j] += __shfl_xor(pq[j], m); }
  }
  int lane = tid & 63, w = tid >> 6;
  if (lane < 4) {
    #pragma unroll
    for (int j = 0; j < 4; j++) { sRedS[w][lane][j] = po[j]; sRedQ[w][lane][j] = pq[j]; }
  }
  __syncthreads();
  if (tid < 16) {
    int o = tid, txo = o >> 2, j = o & 3;
    float s = 0.f, q = 0.f;
    #pragma unroll
    for (int ww = 0; ww < 4; ww++) { s += sRedS[ww][txo][j]; q += sRedQ[ww][txo][j]; }
    int pidx = (n * 32 + tt) * 48 + b * 16 + o;
    pSum2[pidx] = s; pSq2[pidx] = q;
  }
}

// ------------------------------------------------------------------
// Kernel 7: concat branches + bn + residual + relu (2 elems/thread)
// ------------------------------------------------------------------
__global__ __launch_bounds__(256, 4)
void k7_final(const float* __restrict__ x, const bf16* __restrict__ preB,
              const bf16* __restrict__ zbB,
              const float* __restrict__ sc1, const float* __restrict__ sh1,
              const float* __restrict__ sc2, const float* __restrict__ sh2,
              float* __restrict__ out)
{
  const int total2 = 13107200;   // 26214400 / 2
  for (int i2 = blockIdx.x * 256 + threadIdx.x; i2 < total2; i2 += gridDim.x * 256) {
    int idx = i2 * 2;
    int n = idx / 819200, rem = idx - n * 819200;
    int ch = rem / 12800, tv = rem - ch * 12800;
    int b = ch >> 4, o = ch & 15;
    float sc, sh;
    bf16x2 z2;
    if (b < 3) {
      sc = sc2[b * 16 + o]; sh = sh2[b * 16 + o];
      z2 = *(const bf16x2*)&zbB[((b * 32 + n) * 16 + o) * 12800 + tv];
    } else {
      int ko = 48 + o;
      sc = sc1[ko]; sh = sh1[ko];
      z2 = *(const bf16x2*)&preB[(n * 64 + ko) * 12800 + tv];
    }
    float2 xx = *(const float2*)&x[idx];
    float2 res;
    res.x = fmaxf(sc * (float)z2[0] + sh + xx.x, 0.f);
    res.y = fmaxf(sc * (float)z2[1] + sh + xx.y, 0.f);
    *(float2*)&out[idx] = res;
  }
}

// ------------------------------------------------------------------
extern "C" void kernel_launch(void* const* d_in, const int* in_sizes, int n_in,
                              void* d_out, int out_size, void* d_ws, size_t ws_size,
                              hipStream_t stream)
{
  const float* x       = (const float*)d_in[0];
  const float* topo    = (const float*)d_in[1];
  const float* ln_g    = (const float*)d_in[2];
  const float* ln_b    = (const float*)d_in[3];
  const float* qk_w    = (const float*)d_in[4];
  const float* qk_b    = (const float*)d_in[5];
  const float* convd_w = (const float*)d_in[6];
  const float* convd_b = (const float*)d_in[7];
  const float* sagc_g  = (const float*)d_in[8];
  const float* sagc_b  = (const float*)d_in[9];
  const float* w1      = (const float*)d_in[10];
  const float* b1      = (const float*)d_in[11];
  const float* bn1_g   = (const float*)d_in[12];
  const float* bn1_b   = (const float*)d_in[13];
  const float* w2      = (const float*)d_in[14];
  const float* b2      = (const float*)d_in[15];
  const float* bn2_g   = (const float*)d_in[16];
  const float* bn2_b   = (const float*)d_in[17];
  float* out = (float*)d_out;
  float* ws  = (float*)d_ws;

  bf16*  preB  = (bf16*)ws;                    // 26,214,400 bf16 (13,107,200 f)
  bf16*  zbB   = (bf16*)(ws + 13107200);       // 19,660,800 bf16 ( 9,830,400 f)
  float* pSum1 = ws + 22937600;                // 1,048,576
  float* pSq1  = ws + 23986176;                // 1,048,576
  float* pSum2 = ws + 25034752;                // 49,152
  float* pSq2  = ws + 25083904;                // 49,152
  float* scS   = ws + 25133056;  float* shS = scS + 64;
  float* sc1   = scS + 128;      float* sh1 = scS + 192;
  float* sc2   = scS + 256;      float* sh2 = scS + 304;
  bf16*  qkB   = (bf16*)(ws + 25133440);       // 6144 bf16
  bf16*  convB = (bf16*)(ws + 25136512);       // 12288 bf16
  bf16*  w1B   = (bf16*)(ws + 25142656);       // 8192 bf16
  bf16*  saB   = (bf16*)d_out;                 // d_out doubles as sa scratch (bf16)

  const float invN = 1.f / 409600.f;   // N*T*V

  kprepack<<<10, 256, 0, stream>>>(qk_w, convd_w, w1, qkB, convB, w1B);
  k1_sa_sagc<<<dim3(512, 32), 256, 0, stream>>>(x, topo, ln_g, ln_b, qk_b,
                                                qkB, convB, convd_b, saB, pSum1, pSq1);
  kreduce<<<64, 256, 0, stream>>>(pSum1, pSq1, 16384, 64, invN, sagc_g, sagc_b, scS, shS);
  k3_ygc_pre<<<dim3(512, 32), 256, 0, stream>>>(x, saB, scS, shS, w1B, b1,
                                                preB, pSum1, pSq1);
  kreduce<<<64, 256, 0, stream>>>(pSum1, pSq1, 16384, 64, invN, bn1_g, bn1_b, sc1, sh1);
  k5_tcn_branch<<<dim3(32, 3, 32), 256, 0, stream>>>(preB, sc1, sh1, w2, b2,
                                                     zbB, pSum2, pSq2);
  kreduce<<<48, 256, 0, stream>>>(pSum2, pSq2, 1024, 48, invN, bn2_g, bn2_b, sc2, sh2);
  k7_final<<<4096, 256, 0, stream>>>(x, preB, zbB, sc1, sh1, sc2, sh2, out);
}

// Round 4
// 406.053 us; speedup vs baseline: 3.3192x; 1.3109x over previous
//
#include <hip/hip_runtime.h>

// EncodingBlock — Round 4:
//  * Block-contiguous intermediate layouts:
//      saB/preB: [n][t][ch][v] bf16 ; zbB: [b][n][t][o][v] bf16
//    producers write bf16x8 contiguous chunks; consumers read bf16x8.
//  * k1 RACE FIX: sQK stores guarded to rows <25 (rows 28/29 previously
//    overflowed into sMu during phase 3).
//  * k1: QK phase uses all 4 waves; softmax split 2 threads/row.
//  * k7 restructured: one block per (n, 8-t chunk), coalesced x/out.

#define EPS 1e-5f

typedef __bf16 bf16;
typedef __bf16 bf16x8 __attribute__((ext_vector_type(8)));
typedef float f32x4 __attribute__((ext_vector_type(4)));

// ------------------------------------------------------------------
// Prepack weights to MFMA B-fragments.
// ------------------------------------------------------------------
__global__ void kprepack(const float* __restrict__ qk_w, const float* __restrict__ convd_w,
                         const float* __restrict__ w1g,
                         bf16* __restrict__ qkB, bf16* __restrict__ convB, bf16* __restrict__ w1B)
{
  int gid = blockIdx.x * 256 + threadIdx.x;
  if (gid < 384) {                       // qk: (nt,ks,lane) 3*2*64, hi/lo
    int lane = gid & 63, f = gid >> 6;
    int nt = f >> 1, ks = f & 1;
    int row = nt * 16 + (lane & 15);
    int col = ks * 32 + ((lane >> 4) * 8);
    const float* src = &qk_w[row * 64 + col];
    bf16* dh = &qkB[(f * 64 + lane) * 8];
    bf16* dl = dh + 3072;
    #pragma unroll
    for (int j = 0; j < 8; j++) {
      float w = src[j];
      bf16 h = (bf16)w;
      dh[j] = h;
      dl[j] = (bf16)(w - (float)h);
    }
  } else if (gid < 1920) {               // convd: (nt,ks,lane) 4*6*64
    int g = gid - 384;
    int lane = g & 63, f = g >> 6;
    int nt = f / 6, ks = f - nt * 6;
    int k0 = ks * 32 + ((lane >> 4) * 8);
    int h = k0 >> 6, c = k0 & 63;
    int o = nt * 16 + (lane & 15);
    const float* src = &convd_w[(h * 64 + o) * 64 + c];
    bf16* d = &convB[(f * 64 + lane) * 8];
    #pragma unroll
    for (int j = 0; j < 8; j++) d[j] = (bf16)src[j];
  } else if (gid < 2432) {               // w1: (nt,ks,lane) 4*2*64, hi/lo
    int g = gid - 1920;
    int lane = g & 63, f = g >> 6;
    int nt = f >> 1, ks = f & 1;
    int ko = nt * 16 + (lane & 15);
    int c0 = ks * 32 + ((lane >> 4) * 8);
    const float* src = &w1g[ko * 64 + c0];
    bf16* dh = &w1B[(f * 64 + lane) * 8];
    bf16* dl = dh + 4096;
    #pragma unroll
    for (int j = 0; j < 8; j++) {
      float w = src[j];
      bf16 h = (bf16)w;
      dh[j] = h;
      dl[j] = (bf16)(w - (float)h);
    }
  }
}

// ------------------------------------------------------------------
// Kernel 1: fused SelfAttention + SA_GC (pre-BN), MFMA. LDS 25.9 KB.
// ------------------------------------------------------------------
__global__ __launch_bounds__(256, 6)
void k1_sa_sagc(const float* __restrict__ x,
                const float* __restrict__ topo,
                const float* __restrict__ ln_g, const float* __restrict__ ln_b,
                const float* __restrict__ qk_b,
                const bf16* __restrict__ qkB, const bf16* __restrict__ convB,
                const float* __restrict__ convd_b,
                bf16* __restrict__ saB, float* __restrict__ pSum, float* __restrict__ pSq)
{
  const int t = blockIdx.x, n = blockIdx.y, tid = threadIdx.x;
  const int blk = n * 512 + t;
  const int lane = tid & 63, wave = tid >> 6;
  const int rr = lane & 15, co = (lane >> 4) * 8, rq = (lane >> 4) * 4;

  __shared__ __align__(16) float smem[6464];
  bf16*  featT = (bf16*)smem;               // [64][40] bf16   [0..1280)
  bf16*  sAttn = (bf16*)(smem + 1280);      // [3][32][40]     [1280..3200)
  float* sFeat = smem + 3200;               // [25][68] f32    [3200..4900)
  float* sQK   = smem + 4900;               // [25][52] f32    [4900..6200) rows<25 ONLY
  bf16*  zL    = (bf16*)(smem + 3200);      // [32][200] bf16  [3200..6400) overlay
  float* sMu   = smem + 6400;
  float* sRstd = smem + 6432;
  float* sSa   = smem;                      // [64][29] overlay (featT/sAttn dead)

  // (1) load x tile -> sFeat[v][c] f32 and featT[c][j=v] bf16
  for (int idx = tid; idx < 1600; idx += 256) {
    int c = idx / 25, v = idx - c * 25;
    float f = x[((n * 64 + c) * 512 + t) * 25 + v];
    sFeat[v * 68 + c] = f;
    featT[c * 40 + v] = (bf16)f;
  }
  if (tid < 64) {
    #pragma unroll
    for (int j = 25; j < 32; j++) featT[tid * 40 + j] = (bf16)0.f;
  }
  __syncthreads();

  // (2) LayerNorm stats
  {
    int r = tid >> 3, sub = tid & 7;
    if (r < 25) {
      float s = 0.f, q = 0.f;
      #pragma unroll
      for (int c = 0; c < 64; c += 8) { float f = sFeat[r * 68 + c + sub]; s += f; q += f * f; }
      s += __shfl_xor(s, 1); q += __shfl_xor(q, 1);
      s += __shfl_xor(s, 2); q += __shfl_xor(q, 2);
      s += __shfl_xor(s, 4); q += __shfl_xor(q, 4);
      if (sub == 0) {
        float mu = s * (1.f / 64.f);
        float var = q * (1.f / 64.f) - mu * mu;
        sMu[r] = mu; sRstd[r] = rsqrtf(var + EPS);
      }
    }
  }
  __syncthreads();

  // (3) QK projection via MFMA (hi/lo split); all 4 waves.
  //     wave w handles mt = w&1; nts = {0,2} for w<2, {1} for w>=2.
  {
    const int mt = wave & 1;
    bf16x8 Ah[2], Al[2];
    int r0 = mt * 16 + rr;
    bool ok = r0 < 25;
    float mu = ok ? sMu[r0] : 0.f;
    float rs = ok ? sRstd[r0] : 0.f;
    #pragma unroll
    for (int ks = 0; ks < 2; ks++) {
      int c0 = ks * 32 + co;
      float4 fa = make_float4(0.f, 0.f, 0.f, 0.f), fb = fa;
      if (ok) { fa = *(const float4*)&sFeat[r0 * 68 + c0];
                fb = *(const float4*)&sFeat[r0 * 68 + c0 + 4]; }
      float4 g0  = *(const float4*)&ln_g[c0], g1  = *(const float4*)&ln_g[c0 + 4];
      float4 bb0 = *(const float4*)&ln_b[c0], bb1 = *(const float4*)&ln_b[c0 + 4];
      float y[8];
      y[0] = ok ? (fa.x - mu) * rs * g0.x + bb0.x : 0.f;
      y[1] = ok ? (fa.y - mu) * rs * g0.y + bb0.y : 0.f;
      y[2] = ok ? (fa.z - mu) * rs * g0.z + bb0.z : 0.f;
      y[3] = ok ? (fa.w - mu) * rs * g0.w + bb0.w : 0.f;
      y[4] = ok ? (fb.x - mu) * rs * g1.x + bb1.x : 0.f;
      y[5] = ok ? (fb.y - mu) * rs * g1.y + bb1.y : 0.f;
      y[6] = ok ? (fb.z - mu) * rs * g1.z + bb1.z : 0.f;
      y[7] = ok ? (fb.w - mu) * rs * g1.w + bb1.w : 0.f;
      #pragma unroll
      for (int j = 0; j < 8; j++) {
        bf16 h = (bf16)y[j];
        Ah[ks][j] = h;
        Al[ks][j] = (bf16)(y[j] - (float)h);
      }
    }
    #pragma unroll
    for (int q = 0; q < 2; q++) {
      if (wave >= 2 && q > 0) break;
      int nt = (wave < 2) ? (q * 2) : 1;
      float qb = qk_b[nt * 16 + rr];
      f32x4 acc = {qb, qb, qb, qb};
      #pragma unroll
      for (int ks = 0; ks < 2; ks++) {
        bf16x8 Bh = *(const bf16x8*)&qkB[((nt * 2 + ks) * 64 + lane) * 8];
        bf16x8 Bl = *(const bf16x8*)&qkB[3072 + ((nt * 2 + ks) * 64 + lane) * 8];
        acc = __builtin_amdgcn_mfma_f32_16x16x32_bf16(Ah[ks], Bh, acc, 0, 0, 0);
        acc = __builtin_amdgcn_mfma_f32_16x16x32_bf16(Ah[ks], Bl, acc, 0, 0, 0);
        acc = __builtin_amdgcn_mfma_f32_16x16x32_bf16(Al[ks], Bh, acc, 0, 0, 0);
      }
      #pragma unroll
      for (int r = 0; r < 4; r++) {
        int i = mt * 16 + rq + r;
        if (i < 25) sQK[i * 52 + nt * 16 + rr] = acc[r];   // rows<25 only (race fix)
      }
    }
  }
  __syncthreads();

  // (4) dots + softmax + *topo -> sAttn bf16; 2 threads per (h,i) row
  if (tid < 150) {
    int p = tid >> 1, half = tid & 1;
    int h = p / 25, i = p - (p / 25) * 25;
    const float* qr = &sQK[i * 52 + h * 8];
    float4 qa = *(const float4*)qr, qb4 = *(const float4*)(qr + 4);
    const int j0 = half * 13;
    const int cnt = 13 - half;
    float lgv[13];
    float lmax = -3.4e38f;
    #pragma unroll
    for (int jj = 0; jj < 13; jj++) {
      int j = j0 + jj; j = j > 24 ? 24 : j;
      const float* kr = &sQK[j * 52 + 24 + h * 8];
      float4 ka = *(const float4*)kr, kb = *(const float4*)(kr + 4);
      float d = qa.x * ka.x + qa.y * ka.y + qa.z * ka.z + qa.w * ka.w
              + qb4.x * kb.x + qb4.y * kb.y + qb4.z * kb.z + qb4.w * kb.w;
      d *= 0.35355339059327373f;
      lgv[jj] = d;
      lmax = fmaxf(lmax, d);
    }
    lmax = fmaxf(lmax, __shfl_xor(lmax, 1));
    float se = 0.f;
    #pragma unroll
    for (int jj = 0; jj < 13; jj++) {
      float e = __expf(lgv[jj] - lmax);
      lgv[jj] = e;
      if (jj < cnt) se += e;
    }
    se += __shfl_xor(se, 1);
    float inv = 1.f / se;
    bf16* ar = &sAttn[(h * 32 + i) * 40];
    #pragma unroll
    for (int jj = 0; jj < 13; jj++) {
      int j = j0 + jj;
      if (jj < cnt) ar[j] = (bf16)(lgv[jj] * inv * topo[(h * 25 + i) * 25 + j]);
    }
    if (half) {
      #pragma unroll
      for (int j = 25; j < 32; j++) ar[j] = (bf16)0.f;
    }
  } else if (tid >= 192 && tid < 213) {
    int k = tid - 192;
    int h = k / 7, i = 25 + (k - (k / 7) * 7);
    bf16* ar = &sAttn[(h * 32 + i) * 40];
    #pragma unroll
    for (int j = 0; j < 32; j++) ar[j] = (bf16)0.f;
  }
  __syncthreads();

  // (5) z = A_h @ feat via MFMA; wave owns 16 feat-cols
  {
    const int nt = wave;
    bf16x8 Bf = *(const bf16x8*)&featT[(nt * 16 + rr) * 40 + co];
    #pragma unroll
    for (int h = 0; h < 3; h++) {
      #pragma unroll
      for (int mt = 0; mt < 2; mt++) {
        bf16x8 Af = *(const bf16x8*)&sAttn[(h * 32 + mt * 16 + rr) * 40 + co];
        f32x4 az = {0.f, 0.f, 0.f, 0.f};
        az = __builtin_amdgcn_mfma_f32_16x16x32_bf16(Af, Bf, az, 0, 0, 0);
        #pragma unroll
        for (int r = 0; r < 4; r++)
          zL[(mt * 16 + rq + r) * 200 + h * 64 + nt * 16 + rr] = (bf16)az[r];
      }
    }
  }
  __syncthreads();

  // (6) sa = z @ Wcat via MFMA; wave owns 16 output cols
  {
    const int nt = wave;
    int o = nt * 16 + rr;
    float cb = convd_b[o] + convd_b[64 + o] + convd_b[128 + o];
    #pragma unroll
    for (int mt = 0; mt < 2; mt++) {
      f32x4 acc = {cb, cb, cb, cb};
      #pragma unroll
      for (int ks = 0; ks < 6; ks++) {
        bf16x8 Az = *(const bf16x8*)&zL[(mt * 16 + rr) * 200 + ks * 32 + co];
        bf16x8 Bw = *(const bf16x8*)&convB[((nt * 6 + ks) * 64 + lane) * 8];
        acc = __builtin_amdgcn_mfma_f32_16x16x32_bf16(Az, Bw, acc, 0, 0, 0);
      }
      #pragma unroll
      for (int r = 0; r < 4; r++) {
        int i = mt * 16 + rq + r;
        if (i < 25) sSa[o * 29 + i] = acc[r];
      }
    }
  }
  __syncthreads();

  // (7) store saB contiguous [n][t][o][v] via bf16x8 + BN partials
  if (tid < 200) {
    int lin = tid * 8;
    bf16x8 s8;
    #pragma unroll
    for (int e = 0; e < 8; e++) {
      int q = lin + e, o = q / 25, i2 = q - o * 25;
      s8[e] = (bf16)sSa[o * 29 + i2];
    }
    *(bf16x8*)&saB[blk * 1600 + lin] = s8;
  }
  if (tid < 64) {
    float s = 0.f, q = 0.f;
    #pragma unroll
    for (int i = 0; i < 25; i++) { float v = sSa[tid * 29 + i]; s += v; q += v * v; }
    pSum[blk * 64 + tid] = s;
    pSq [blk * 64 + tid] = q;
  }
}

// ------------------------------------------------------------------
// BN-stat reduce: one block per channel; partials layout [part][C]
// ------------------------------------------------------------------
__global__ __launch_bounds__(256, 4)
void kreduce(const float* __restrict__ pS, const float* __restrict__ pQ,
             int npart, int C, float invN,
             const float* __restrict__ g, const float* __restrict__ bta,
             float* __restrict__ sc, float* __restrict__ sh)
{
  int c = blockIdx.x, tid = threadIdx.x;
  float s = 0.f, q = 0.f;
  for (int i = tid; i < npart; i += 256) { s += pS[i * C + c]; q += pQ[i * C + c]; }
  #pragma unroll
  for (int m = 1; m < 64; m <<= 1) { s += __shfl_xor(s, m); q += __shfl_xor(q, m); }
  __shared__ float rs[4], rq[4];
  int w = tid >> 6;
  if ((tid & 63) == 0) { rs[w] = s; rq[w] = q; }
  __syncthreads();
  if (tid == 0) {
    float S = rs[0] + rs[1] + rs[2] + rs[3];
    float Q = rq[0] + rq[1] + rq[2] + rq[3];
    float mu = S * invN, var = Q * invN - mu * mu;
    float r = rsqrtf(var + EPS);
    sc[c] = g[c] * r;
    sh[c] = bta[c] - mu * g[c] * r;
  }
}

// ------------------------------------------------------------------
// Kernel 3: y_gc = relu(bn(sa)+x); pre = y_gc @ W1 + b1 via MFMA (hi/lo)
// saB/preB layout: [n][t][ch][v] contiguous per (n,t).
// ------------------------------------------------------------------
__global__ __launch_bounds__(256, 8)
void k3_ygc_pre(const float* __restrict__ x, const bf16* __restrict__ saB,
                const float* __restrict__ scS, const float* __restrict__ shS,
                const bf16* __restrict__ w1B, const float* __restrict__ b1,
                bf16* __restrict__ preB, float* __restrict__ pSum, float* __restrict__ pSq)
{
  const int t = blockIdx.x, n = blockIdx.y, tid = threadIdx.x;
  const int blk = n * 512 + t;
  const int lane = tid & 63, wave = tid >> 6;
  const int rr = lane & 15, co = (lane >> 4) * 8, rq = (lane >> 4) * 4;

  __shared__ __align__(16) float sYgc[25 * 68];
  __shared__ float sPre[64 * 29];

  if (tid < 200) {
    int lin = tid * 8;
    bf16x8 s8 = *(const bf16x8*)&saB[blk * 1600 + lin];
    #pragma unroll
    for (int e = 0; e < 8; e++) {
      int q = lin + e, c = q / 25, v = q - c * 25;
      float val = scS[c] * (float)s8[e] + shS[c] + x[((n * 64 + c) * 512 + t) * 25 + v];
      sYgc[v * 68 + c] = fmaxf(val, 0.f);
    }
  }
  __syncthreads();

  {
    const int nt = wave;  // output cols nt*16..+15
    bf16x8 Ah[2][2], Al[2][2];
    #pragma unroll
    for (int mt = 0; mt < 2; mt++) {
      int r0 = mt * 16 + rr;
      bool ok = r0 < 25;
      #pragma unroll
      for (int ks = 0; ks < 2; ks++) {
        float v[8];
        if (ok) {
          float4 fa = *(const float4*)&sYgc[r0 * 68 + ks * 32 + co];
          float4 fb = *(const float4*)&sYgc[r0 * 68 + ks * 32 + co + 4];
          v[0]=fa.x; v[1]=fa.y; v[2]=fa.z; v[3]=fa.w;
          v[4]=fb.x; v[5]=fb.y; v[6]=fb.z; v[7]=fb.w;
        } else {
          #pragma unroll
          for (int j = 0; j < 8; j++) v[j] = 0.f;
        }
        #pragma unroll
        for (int j = 0; j < 8; j++) {
          bf16 h = (bf16)v[j];
          Ah[mt][ks][j] = h;
          Al[mt][ks][j] = (bf16)(v[j] - (float)h);
        }
      }
    }
    float bb = b1[nt * 16 + rr];
    #pragma unroll
    for (int mt = 0; mt < 2; mt++) {
      f32x4 acc = {bb, bb, bb, bb};
      #pragma unroll
      for (int ks = 0; ks < 2; ks++) {
        bf16x8 Bh = *(const bf16x8*)&w1B[((nt * 2 + ks) * 64 + lane) * 8];
        bf16x8 Bl = *(const bf16x8*)&w1B[4096 + ((nt * 2 + ks) * 64 + lane) * 8];
        acc = __builtin_amdgcn_mfma_f32_16x16x32_bf16(Ah[mt][ks], Bh, acc, 0, 0, 0);
        acc = __builtin_amdgcn_mfma_f32_16x16x32_bf16(Ah[mt][ks], Bl, acc, 0, 0, 0);
        acc = __builtin_amdgcn_mfma_f32_16x16x32_bf16(Al[mt][ks], Bh, acc, 0, 0, 0);
      }
      #pragma unroll
      for (int r = 0; r < 4; r++) {
        int i = mt * 16 + rq + r;
        if (i < 25) sPre[(nt * 16 + rr) * 29 + i] = acc[r];
      }
    }
  }
  __syncthreads();

  if (tid < 200) {
    int lin = tid * 8;
    bf16x8 p8;
    #pragma unroll
    for (int e = 0; e < 8; e++) {
      int q = lin + e, ko = q / 25, v = q - ko * 25;
      p8[e] = (bf16)sPre[ko * 29 + v];
    }
    *(bf16x8*)&preB[blk * 1600 + lin] = p8;
  }
  if (tid < 64) {
    float s = 0.f, q = 0.f;
    #pragma unroll
    for (int i = 0; i < 25; i++) { float v = sPre[tid * 29 + i]; s += v; q += v * v; }
    pSum[blk * 64 + tid] = s;
    pSq [blk * 64 + tid] = q;
  }
}

// ------------------------------------------------------------------
// Kernel 5: TCN branches; preB [n][t][ch][v], zbB [b][n][t][o][v]
// ------------------------------------------------------------------
template<int D>
__device__ __forceinline__ void conv5(const float* __restrict__ sIn, const float* __restrict__ sW,
                                      float4 bias, int o4, int v, int tb, float acc[8][4])
{
  #pragma unroll
  for (int s = 0; s < 8; s++) {
    acc[s][0] = bias.x; acc[s][1] = bias.y; acc[s][2] = bias.z; acc[s][3] = bias.w;
  }
  const int NW = 8 + 4 * D;
  for (int ic = 0; ic < 16; ic++) {
    float4 wk[5];
    #pragma unroll
    for (int kt = 0; kt < 5; kt++) wk[kt] = *(const float4*)&sW[(ic * 5 + kt) * 16 + o4];
    float xw[8 + 4 * D];
    #pragma unroll
    for (int w = 0; w < NW; w++) xw[w] = sIn[(ic * 24 + (tb - 2 * D + w + 4)) * 25 + v];
    #pragma unroll
    for (int s = 0; s < 8; s++)
      #pragma unroll
      for (int kt = 0; kt < 5; kt++) {
        float xv = xw[s + kt * D];
        acc[s][0] += xv * wk[kt].x; acc[s][1] += xv * wk[kt].y;
        acc[s][2] += xv * wk[kt].z; acc[s][3] += xv * wk[kt].w;
      }
  }
}

__global__ __launch_bounds__(256, 2)
void k5_tcn_branch(const bf16* __restrict__ preB,
                   const float* __restrict__ sc1, const float* __restrict__ sh1,
                   const float* __restrict__ w2, const float* __restrict__ b2,
                   bf16* __restrict__ zbB, float* __restrict__ pSum2, float* __restrict__ pSq2)
{
  const int tt = blockIdx.x, b = blockIdx.y, n = blockIdx.z;
  const int tid = threadIdx.x, t0 = tt * 16;
  __shared__ __align__(16) float sIn[16 * 24 * 25];
  __shared__ __align__(16) float sW[16 * 5 * 16];
  __shared__ float sRedS[4][4][4], sRedQ[4][4][4];

  // stage: 24 t-rows x 400 contiguous bf16 each (this branch's 16 channels)
  for (int idx = tid; idx < 1200; idx += 256) {
    int r = idx / 50, k8 = idx - r * 50;
    int gt = t0 - 4 + r;
    int lin = k8 * 8;
    if (gt >= 0 && gt < 512) {
      bf16x8 p8 = *(const bf16x8*)&preB[((n * 512 + gt) * 64 + b * 16) * 25 + lin];
      #pragma unroll
      for (int e = 0; e < 8; e++) {
        int q = lin + e, ic = q / 25, v = q - ic * 25;
        int ch = b * 16 + ic;
        sIn[(ic * 24 + r) * 25 + v] = fmaxf(sc1[ch] * (float)p8[e] + sh1[ch], 0.f);
      }
    } else {
      #pragma unroll
      for (int e = 0; e < 8; e++) {
        int q = lin + e, ic = q / 25, v = q - ic * 25;
        sIn[(ic * 24 + r) * 25 + v] = 0.f;
      }
    }
  }
  if (b < 2)
    for (int idx = tid; idx < 1280; idx += 256) {
      int o = idx / 80, rem = idx - o * 80;
      int ic = rem / 5, kt = rem - ic * 5;
      sW[(ic * 5 + kt) * 16 + o] = w2[((b * 16 + o) * 16 + ic) * 5 + kt];
    }
  __syncthreads();

  float po[4] = {0.f, 0.f, 0.f, 0.f}, pq[4] = {0.f, 0.f, 0.f, 0.f};
  if (tid < 200) {
    int tx = tid & 3, o4 = tx * 4;
    int g = tid >> 2;
    int v = g % 25, th = g / 25;
    int tb = th * 8;
    float acc[8][4];
    if (b == 0)      conv5<1>(sIn, sW, *(const float4*)&b2[o4],      o4, v, tb, acc);
    else if (b == 1) conv5<2>(sIn, sW, *(const float4*)&b2[16 + o4], o4, v, tb, acc);
    else {
      #pragma unroll
      for (int s = 0; s < 8; s++)
        #pragma unroll
        for (int j = 0; j < 4; j++) {
          int o = o4 + j, r = tb + s + 4;
          float a = sIn[(o * 24 + r - 1) * 25 + v];
          float m = sIn[(o * 24 + r    ) * 25 + v];
          float c = sIn[(o * 24 + r + 1) * 25 + v];
          acc[s][j] = fmaxf(fmaxf(a, m), c);
        }
    }
    #pragma unroll
    for (int s = 0; s < 8; s++) {
      int gt = t0 + tb + s;
      #pragma unroll
      for (int j = 0; j < 4; j++) {
        float val = acc[s][j];
        zbB[(((b * 32 + n) * 512 + gt) * 16 + (o4 + j)) * 25 + v] = (bf16)val;
        po[j] += val; pq[j] += val * val;
      }
    }
  }
  #pragma unroll
  for (int m = 4; m < 64; m <<= 1) {
    #pragma unroll
    for (int j = 0; j < 4; j++) { po[j] += __shfl_xor(po[j], m); pq[j] += __shfl_xor(pq[j], m); }
  }
  int lane = tid & 63, w = tid >> 6;
  if (lane < 4) {
    #pragma unroll
    for (int j = 0; j < 4; j++) { sRedS[w][lane][j] = po[j]; sRedQ[w][lane][j] = pq[j]; }
  }
  __syncthreads();
  if (tid < 16) {
    int o = tid, txo = o >> 2, j = o & 3;
    float s = 0.f, q = 0.f;
    #pragma unroll
    for (int ww = 0; ww < 4; ww++) { s += sRedS[ww][txo][j]; q += sRedQ[ww][txo][j]; }
    int pidx = (n * 32 + tt) * 48 + b * 16 + o;
    pSum2[pidx] = s; pSq2[pidx] = q;
  }
}

// ------------------------------------------------------------------
// Kernel 7: concat + bn + residual + relu. Block per (n, 8-t chunk).
// ------------------------------------------------------------------
__global__ __launch_bounds__(256, 8)
void k7_final(const float* __restrict__ x, const bf16* __restrict__ preB,
              const bf16* __restrict__ zbB,
              const float* __restrict__ sc1, const float* __restrict__ sh1,
              const float* __restrict__ sc2, const float* __restrict__ sh2,
              float* __restrict__ out)
{
  const int bid = blockIdx.x;            // 2048 = 32 n * 64 chunks
  const int n = bid >> 6, tc = bid & 63;
  const int t0 = tc * 8;
  for (int e = threadIdx.x; e < 12800; e += 256) {
    int ch = e / 200, r = e - ch * 200;  // r = local t*25 + v
    int tl = r / 25, v = r - tl * 25;
    int t = t0 + tl;
    int b = ch >> 4, o = ch & 15;
    float val;
    if (b < 3) {
      val = sc2[b * 16 + o] * (float)zbB[(((b * 32 + n) * 512 + t) * 16 + o) * 25 + v]
          + sh2[b * 16 + o];
    } else {
      int ko = 48 + o;
      val = sc1[ko] * (float)preB[((n * 512 + t) * 64 + ko) * 25 + v] + sh1[ko];
    }
    int ax = (n * 64 + ch) * 12800 + t * 25 + v;
    out[ax] = fmaxf(val + x[ax], 0.f);
  }
}

// ------------------------------------------------------------------
extern "C" void kernel_launch(void* const* d_in, const int* in_sizes, int n_in,
                              void* d_out, int out_size, void* d_ws, size_t ws_size,
                              hipStream_t stream)
{
  const float* x       = (const float*)d_in[0];
  const float* topo    = (const float*)d_in[1];
  const float* ln_g    = (const float*)d_in[2];
  const float* ln_b    = (const float*)d_in[3];
  const float* qk_w    = (const float*)d_in[4];
  const float* qk_b    = (const float*)d_in[5];
  const float* convd_w = (const float*)d_in[6];
  const float* convd_b = (const float*)d_in[7];
  const float* sagc_g  = (const float*)d_in[8];
  const float* sagc_b  = (const float*)d_in[9];
  const float* w1      = (const float*)d_in[10];
  const float* b1      = (const float*)d_in[11];
  const float* bn1_g   = (const float*)d_in[12];
  const float* bn1_b   = (const float*)d_in[13];
  const float* w2      = (const float*)d_in[14];
  const float* b2      = (const float*)d_in[15];
  const float* bn2_g   = (const float*)d_in[16];
  const float* bn2_b   = (const float*)d_in[17];
  float* out = (float*)d_out;
  float* ws  = (float*)d_ws;

  bf16*  preB  = (bf16*)ws;                    // 26,214,400 bf16
  bf16*  zbB   = (bf16*)(ws + 13107200);       // 19,660,800 bf16
  float* pSum1 = ws + 22937600;                // 1,048,576
  float* pSq1  = ws + 23986176;                // 1,048,576
  float* pSum2 = ws + 25034752;                // 49,152
  float* pSq2  = ws + 25083904;                // 49,152
  float* scS   = ws + 25133056;  float* shS = scS + 64;
  float* sc1   = scS + 128;      float* sh1 = scS + 192;
  float* sc2   = scS + 256;      float* sh2 = scS + 304;
  bf16*  qkB   = (bf16*)(ws + 25133440);       // 6144 bf16
  bf16*  convB = (bf16*)(ws + 25136512);       // 12288 bf16
  bf16*  w1B   = (bf16*)(ws + 25142656);       // 8192 bf16
  bf16*  saB   = (bf16*)d_out;                 // d_out doubles as sa scratch

  const float invN = 1.f / 409600.f;   // N*T*V

  kprepack<<<10, 256, 0, stream>>>(qk_w, convd_w, w1, qkB, convB, w1B);
  k1_sa_sagc<<<dim3(512, 32), 256, 0, stream>>>(x, topo, ln_g, ln_b, qk_b,
                                                qkB, convB, convd_b, saB, pSum1, pSq1);
  kreduce<<<64, 256, 0, stream>>>(pSum1, pSq1, 16384, 64, invN, sagc_g, sagc_b, scS, shS);
  k3_ygc_pre<<<dim3(512, 32), 256, 0, stream>>>(x, saB, scS, shS, w1B, b1,
                                                preB, pSum1, pSq1);
  kreduce<<<64, 256, 0, stream>>>(pSum1, pSq1, 16384, 64, invN, bn1_g, bn1_b, sc1, sh1);
  k5_tcn_branch<<<dim3(32, 3, 32), 256, 0, stream>>>(preB, sc1, sh1, w2, b2,
                                                     zbB, pSum2, pSq2);
  kreduce<<<48, 256, 0, stream>>>(pSum2, pSq2, 1024, 48, invN, bn2_g, bn2_b, sc2, sh2);
  k7_final<<<2048, 256, 0, stream>>>(x, preB, zbB, sc1, sh1, sc2, sh2, out);
}

// Round 6
// 364.190 us; speedup vs baseline: 3.7007x; 1.1150x over previous
//
#include <hip/hip_runtime.h>

// EncodingBlock — Round 6: fixes round-5 LDS overlap bug in k1.
//  featT is 1280 FLOATS (2560 bf16); round 5 placed yH at +640, clobbering
//  featT rows 32..63 and racing zL with featT reads in P5. New map:
//   featT [0,1280) | yH [1280,2180) | yL [2180,3080) | zL ovl [1280,4480)
//   sPart/sQK/sSa [4480,..) | sAttn [5880,7800) | lnG/lnB [7800,7928)
//  All other round-5 changes retained (y-once-to-LDS, in-load LN partials,
//  2-level BN reduce, k3 yH/yL precompute).

#define EPS 1e-5f

typedef __bf16 bf16;
typedef __bf16 bf16x8 __attribute__((ext_vector_type(8)));
typedef float f32x4 __attribute__((ext_vector_type(4)));

// ------------------------------------------------------------------
// Prepack weights to MFMA B-fragments.
// ------------------------------------------------------------------
__global__ void kprepack(const float* __restrict__ qk_w, const float* __restrict__ convd_w,
                         const float* __restrict__ w1g,
                         bf16* __restrict__ qkB, bf16* __restrict__ convB, bf16* __restrict__ w1B)
{
  int gid = blockIdx.x * 256 + threadIdx.x;
  if (gid < 384) {                       // qk: (nt,ks,lane) 3*2*64, hi/lo
    int lane = gid & 63, f = gid >> 6;
    int nt = f >> 1, ks = f & 1;
    int row = nt * 16 + (lane & 15);
    int col = ks * 32 + ((lane >> 4) * 8);
    const float* src = &qk_w[row * 64 + col];
    bf16* dh = &qkB[(f * 64 + lane) * 8];
    bf16* dl = dh + 3072;
    #pragma unroll
    for (int j = 0; j < 8; j++) {
      float w = src[j];
      bf16 h = (bf16)w;
      dh[j] = h;
      dl[j] = (bf16)(w - (float)h);
    }
  } else if (gid < 1920) {               // convd: (nt,ks,lane) 4*6*64
    int g = gid - 384;
    int lane = g & 63, f = g >> 6;
    int nt = f / 6, ks = f - nt * 6;
    int k0 = ks * 32 + ((lane >> 4) * 8);
    int h = k0 >> 6, c = k0 & 63;
    int o = nt * 16 + (lane & 15);
    const float* src = &convd_w[(h * 64 + o) * 64 + c];
    bf16* d = &convB[(f * 64 + lane) * 8];
    #pragma unroll
    for (int j = 0; j < 8; j++) d[j] = (bf16)src[j];
  } else if (gid < 2432) {               // w1: (nt,ks,lane) 4*2*64, hi/lo
    int g = gid - 1920;
    int lane = g & 63, f = g >> 6;
    int nt = f >> 1, ks = f & 1;
    int ko = nt * 16 + (lane & 15);
    int c0 = ks * 32 + ((lane >> 4) * 8);
    const float* src = &w1g[ko * 64 + c0];
    bf16* dh = &w1B[(f * 64 + lane) * 8];
    bf16* dl = dh + 4096;
    #pragma unroll
    for (int j = 0; j < 8; j++) {
      float w = src[j];
      bf16 h = (bf16)w;
      dh[j] = h;
      dl[j] = (bf16)(w - (float)h);
    }
  }
}

// ------------------------------------------------------------------
// Kernel 1: fused SelfAttention + SA_GC (pre-BN). LDS 31.7 KB -> 5/CU.
// ------------------------------------------------------------------
__global__ __launch_bounds__(256, 5)
void k1_sa_sagc(const float* __restrict__ x,
                const float* __restrict__ topo,
                const float* __restrict__ ln_g, const float* __restrict__ ln_b,
                const float* __restrict__ qk_b,
                const bf16* __restrict__ qkB, const bf16* __restrict__ convB,
                const float* __restrict__ convd_b,
                bf16* __restrict__ saB, float* __restrict__ pSum, float* __restrict__ pSq)
{
  const int t = blockIdx.x, n = blockIdx.y, tid = threadIdx.x;
  const int blk = n * 512 + t;
  const int lane = tid & 63, wave = tid >> 6;
  const int rr = lane & 15, co = (lane >> 4) * 8, rq = (lane >> 4) * 4;

  __shared__ __align__(16) float smem[7928];
  bf16*  featT  = (bf16*)smem;               // [64][40] bf16 = 2560 bf16 -> [0, 1280)
  bf16*  yH     = (bf16*)(smem + 1280);      // [25][72] bf16 -> [1280, 2180)
  bf16*  yL     = (bf16*)(smem + 2180);      // [2180, 3080)
  bf16*  zL     = (bf16*)(smem + 1280);      // [32][200] bf16 -> [1280, 4480) overlay (yH/yL dead)
  float* sPartS = smem + 4480;               // [25][4]  [4480, 4580)
  float* sPartQ = smem + 4580;               // [25][4]  [4580, 4680)
  float* sQK    = smem + 4480;               // [25][56] [4480, 5880) overlay (sPart dead)
  bf16*  sAttn  = (bf16*)(smem + 5880);      // [3][32][40] -> [5880, 7800)
  float* sSa    = smem + 4480;               // [64][29] [4480, 6336) overlay (sQK/sAttn dead)
  float* sLnG   = smem + 7800;               // [64]
  float* sLnB   = smem + 7864;               // [64] -> ends 7928

  // P1: load x (coalesced, kept in regs), featT bf16, LN partials
  const int v = tid & 31, cb = tid >> 5;
  float xv[8];
  {
    const float* xp = &x[((n * 64 + cb) * 512 + t) * 25 + (v < 25 ? v : 0)];
    float s = 0.f, q = 0.f;
    #pragma unroll
    for (int k = 0; k < 8; k++) {
      float f = (v < 25) ? xp[k * 102400] : 0.f;   // 102400 = 8*512*25
      xv[k] = f;
      featT[(cb + 8 * k) * 40 + v] = (bf16)f;
      s += f; q += f * f;
    }
    s += __shfl_xor(s, 32); q += __shfl_xor(q, 32);
    if (lane < 32 && v < 25) { sPartS[v * 4 + wave] = s; sPartQ[v * 4 + wave] = q; }
    if (tid < 64) { sLnG[tid] = ln_g[tid]; sLnB[tid] = ln_b[tid]; }
  }
  __syncthreads();

  // P2: finalize stats (redundant per thread) + y = LN(x) -> yH/yL bf16
  if (v < 25) {
    float S = sPartS[v * 4] + sPartS[v * 4 + 1] + sPartS[v * 4 + 2] + sPartS[v * 4 + 3];
    float Q = sPartQ[v * 4] + sPartQ[v * 4 + 1] + sPartQ[v * 4 + 2] + sPartQ[v * 4 + 3];
    float mu = S * (1.f / 64.f);
    float rstd = rsqrtf(Q * (1.f / 64.f) - mu * mu + EPS);
    #pragma unroll
    for (int k = 0; k < 8; k++) {
      int c = cb + 8 * k;
      float yv = (xv[k] - mu) * rstd * sLnG[c] + sLnB[c];
      bf16 h = (bf16)yv;
      yH[v * 72 + c] = h;
      yL[v * 72 + c] = (bf16)(yv - (float)h);
    }
  }
  __syncthreads();

  // P3: QK projection via MFMA (hi/lo). A-frags = pure LDS b128 reads.
  {
    const int mt = wave & 1;
    const int r0 = mt * 16 + rr;               // rows >=25 read junk -> discarded
    bf16x8 Ah[2], Al[2];
    #pragma unroll
    for (int ks = 0; ks < 2; ks++) {
      Ah[ks] = *(const bf16x8*)&yH[r0 * 72 + ks * 32 + co];
      Al[ks] = *(const bf16x8*)&yL[r0 * 72 + ks * 32 + co];
    }
    #pragma unroll
    for (int q = 0; q < 2; q++) {
      if (wave >= 2 && q > 0) break;
      int nt = (wave < 2) ? (q * 2) : 1;
      float qb = qk_b[nt * 16 + rr];
      f32x4 acc = {qb, qb, qb, qb};
      #pragma unroll
      for (int ks = 0; ks < 2; ks++) {
        bf16x8 Bh = *(const bf16x8*)&qkB[((nt * 2 + ks) * 64 + lane) * 8];
        bf16x8 Bl = *(const bf16x8*)&qkB[3072 + ((nt * 2 + ks) * 64 + lane) * 8];
        acc = __builtin_amdgcn_mfma_f32_16x16x32_bf16(Ah[ks], Bh, acc, 0, 0, 0);
        acc = __builtin_amdgcn_mfma_f32_16x16x32_bf16(Ah[ks], Bl, acc, 0, 0, 0);
        acc = __builtin_amdgcn_mfma_f32_16x16x32_bf16(Al[ks], Bh, acc, 0, 0, 0);
      }
      #pragma unroll
      for (int r = 0; r < 4; r++) {
        int i = mt * 16 + rq + r;
        if (i < 25) sQK[i * 56 + nt * 16 + rr] = acc[r];
      }
    }
  }
  __syncthreads();

  // P4: dots + softmax + *topo -> sAttn bf16; 2 threads per (h,i) row
  if (tid < 150) {
    int p = tid >> 1, half = tid & 1;
    int h = p / 25, i = p - (p / 25) * 25;
    const float* qr = &sQK[i * 56 + h * 8];
    float4 qa = *(const float4*)qr, qb4 = *(const float4*)(qr + 4);
    const int j0 = half * 13;
    const int cnt = 13 - half;
    float lgv[13];
    float lmax = -3.4e38f;
    #pragma unroll
    for (int jj = 0; jj < 13; jj++) {
      int j = j0 + jj; j = j > 24 ? 24 : j;
      const float* kr = &sQK[j * 56 + 24 + h * 8];
      float4 ka = *(const float4*)kr, kb = *(const float4*)(kr + 4);
      float d = qa.x * ka.x + qa.y * ka.y + qa.z * ka.z + qa.w * ka.w
              + qb4.x * kb.x + qb4.y * kb.y + qb4.z * kb.z + qb4.w * kb.w;
      d *= 0.35355339059327373f;
      lgv[jj] = d;
      lmax = fmaxf(lmax, d);
    }
    lmax = fmaxf(lmax, __shfl_xor(lmax, 1));
    float se = 0.f;
    #pragma unroll
    for (int jj = 0; jj < 13; jj++) {
      float e = __expf(lgv[jj] - lmax);
      lgv[jj] = e;
      if (jj < cnt) se += e;
    }
    se += __shfl_xor(se, 1);
    float inv = 1.f / se;
    bf16* ar = &sAttn[(h * 32 + i) * 40];
    #pragma unroll
    for (int jj = 0; jj < 13; jj++) {
      int j = j0 + jj;
      if (jj < cnt) ar[j] = (bf16)(lgv[jj] * inv * topo[(h * 25 + i) * 25 + j]);
    }
    if (half) {
      #pragma unroll
      for (int j = 25; j < 32; j++) ar[j] = (bf16)0.f;
    }
  } else if (tid >= 192 && tid < 213) {
    int k = tid - 192;
    int h = k / 7, i = 25 + (k - (k / 7) * 7);
    bf16* ar = &sAttn[(h * 32 + i) * 40];
    #pragma unroll
    for (int j = 0; j < 32; j++) ar[j] = (bf16)0.f;
  }
  __syncthreads();

  // P5: z = A_h @ feat via MFMA; wave owns 16 feat-cols
  {
    const int nt = wave;
    bf16x8 Bf = *(const bf16x8*)&featT[(nt * 16 + rr) * 40 + co];
    #pragma unroll
    for (int h = 0; h < 3; h++) {
      #pragma unroll
      for (int mt = 0; mt < 2; mt++) {
        bf16x8 Af = *(const bf16x8*)&sAttn[(h * 32 + mt * 16 + rr) * 40 + co];
        f32x4 az = {0.f, 0.f, 0.f, 0.f};
        az = __builtin_amdgcn_mfma_f32_16x16x32_bf16(Af, Bf, az, 0, 0, 0);
        #pragma unroll
        for (int r = 0; r < 4; r++)
          zL[(mt * 16 + rq + r) * 200 + h * 64 + nt * 16 + rr] = (bf16)az[r];
      }
    }
  }
  __syncthreads();

  // P6: sa = z @ Wcat via MFMA; wave owns 16 output cols
  {
    const int nt = wave;
    int o = nt * 16 + rr;
    float cb2 = convd_b[o] + convd_b[64 + o] + convd_b[128 + o];
    #pragma unroll
    for (int mt = 0; mt < 2; mt++) {
      f32x4 acc = {cb2, cb2, cb2, cb2};
      #pragma unroll
      for (int ks = 0; ks < 6; ks++) {
        bf16x8 Az = *(const bf16x8*)&zL[(mt * 16 + rr) * 200 + ks * 32 + co];
        bf16x8 Bw = *(const bf16x8*)&convB[((nt * 6 + ks) * 64 + lane) * 8];
        acc = __builtin_amdgcn_mfma_f32_16x16x32_bf16(Az, Bw, acc, 0, 0, 0);
      }
      #pragma unroll
      for (int r = 0; r < 4; r++) {
        int i = mt * 16 + rq + r;
        if (i < 25) sSa[o * 29 + i] = acc[r];
      }
    }
  }
  __syncthreads();

  // P7: store saB contiguous [n][t][o][v] via bf16x8 + BN partials
  if (tid < 200) {
    int lin = tid * 8;
    bf16x8 s8;
    #pragma unroll
    for (int e = 0; e < 8; e++) {
      int q = lin + e, o = q / 25, i2 = q - o * 25;
      s8[e] = (bf16)sSa[o * 29 + i2];
    }
    *(bf16x8*)&saB[blk * 1600 + lin] = s8;
  }
  if (tid < 64) {
    float s = 0.f, q = 0.f;
    #pragma unroll
    for (int i = 0; i < 25; i++) { float v2 = sSa[tid * 29 + i]; s += v2; q += v2 * v2; }
    pSum[blk * 64 + tid] = s;
    pSq [blk * 64 + tid] = q;
  }
}

// ------------------------------------------------------------------
// kpart: coalesced first-level reduce of [16384][64] partials -> [256][64]
// ------------------------------------------------------------------
__global__ __launch_bounds__(256, 8)
void kpart(const float* __restrict__ pS, const float* __restrict__ pQ,
           float* __restrict__ oS, float* __restrict__ oQ)
{
  const int g = blockIdx.x, tid = threadIdx.x;
  const int c = tid & 63, r = tid >> 6;
  float s = 0.f, q = 0.f;
  for (int i = 0; i < 16; i++) {
    int b = g * 64 + r * 16 + i;
    s += pS[b * 64 + c]; q += pQ[b * 64 + c];
  }
  __shared__ float ls[4][64], lq[4][64];
  ls[r][c] = s; lq[r][c] = q;
  __syncthreads();
  if (tid < 64) {
    oS[g * 64 + tid] = ls[0][tid] + ls[1][tid] + ls[2][tid] + ls[3][tid];
    oQ[g * 64 + tid] = lq[0][tid] + lq[1][tid] + lq[2][tid] + lq[3][tid];
  }
}

// ------------------------------------------------------------------
// BN-stat reduce: one block per channel; partials layout [part][C]
// ------------------------------------------------------------------
__global__ __launch_bounds__(256, 4)
void kreduce(const float* __restrict__ pS, const float* __restrict__ pQ,
             int npart, int C, float invN,
             const float* __restrict__ g, const float* __restrict__ bta,
             float* __restrict__ sc, float* __restrict__ sh)
{
  int c = blockIdx.x, tid = threadIdx.x;
  float s = 0.f, q = 0.f;
  for (int i = tid; i < npart; i += 256) { s += pS[i * C + c]; q += pQ[i * C + c]; }
  #pragma unroll
  for (int m = 1; m < 64; m <<= 1) { s += __shfl_xor(s, m); q += __shfl_xor(q, m); }
  __shared__ float rs[4], rq[4];
  int w = tid >> 6;
  if ((tid & 63) == 0) { rs[w] = s; rq[w] = q; }
  __syncthreads();
  if (tid == 0) {
    float S = rs[0] + rs[1] + rs[2] + rs[3];
    float Q = rq[0] + rq[1] + rq[2] + rq[3];
    float mu = S * invN, var = Q * invN - mu * mu;
    float r = rsqrtf(var + EPS);
    sc[c] = g[c] * r;
    sh[c] = bta[c] - mu * g[c] * r;
  }
}

// ------------------------------------------------------------------
// Kernel 3: y_gc = relu(bn(sa)+x); pre = y_gc @ W1 + b1 via MFMA (hi/lo)
// yH/yL precomputed once into LDS. LDS 14.6 KB.
// ------------------------------------------------------------------
__global__ __launch_bounds__(256, 8)
void k3_ygc_pre(const float* __restrict__ x, const bf16* __restrict__ saB,
                const float* __restrict__ scS, const float* __restrict__ shS,
                const bf16* __restrict__ w1B, const float* __restrict__ b1,
                bf16* __restrict__ preB, float* __restrict__ pSum, float* __restrict__ pSq)
{
  const int t = blockIdx.x, n = blockIdx.y, tid = threadIdx.x;
  const int blk = n * 512 + t;
  const int lane = tid & 63, wave = tid >> 6;
  const int rr = lane & 15, co = (lane >> 4) * 8, rq = (lane >> 4) * 4;

  __shared__ __align__(16) float smem[3656];
  bf16*  yH   = (bf16*)smem;             // [25][72] bf16 -> [0, 900)
  bf16*  yL   = (bf16*)(smem + 900);     // [900, 1800)
  float* sPre = smem + 1800;             // [64][29] [1800, 3656)

  if (tid < 200) {
    int lin = tid * 8;
    int c = lin / 25, v = lin - c * 25;
    bf16x8 s8 = *(const bf16x8*)&saB[blk * 1600 + lin];
    #pragma unroll
    for (int e = 0; e < 8; e++) {
      float val = scS[c] * (float)s8[e] + shS[c] + x[((n * 64 + c) * 512 + t) * 25 + v];
      val = fmaxf(val, 0.f);
      bf16 h = (bf16)val;
      yH[v * 72 + c] = h;
      yL[v * 72 + c] = (bf16)(val - (float)h);
      if (++v == 25) { v = 0; c++; }
    }
  }
  __syncthreads();

  {
    const int nt = wave;  // output cols nt*16..+15
    bf16x8 Ah[2][2], Al[2][2];
    #pragma unroll
    for (int mt = 0; mt < 2; mt++) {
      int r0 = mt * 16 + rr;               // rows >=25 read junk -> discarded
      #pragma unroll
      for (int ks = 0; ks < 2; ks++) {
        Ah[mt][ks] = *(const bf16x8*)&yH[r0 * 72 + ks * 32 + co];
        Al[mt][ks] = *(const bf16x8*)&yL[r0 * 72 + ks * 32 + co];
      }
    }
    float bb = b1[nt * 16 + rr];
    #pragma unroll
    for (int mt = 0; mt < 2; mt++) {
      f32x4 acc = {bb, bb, bb, bb};
      #pragma unroll
      for (int ks = 0; ks < 2; ks++) {
        bf16x8 Bh = *(const bf16x8*)&w1B[((nt * 2 + ks) * 64 + lane) * 8];
        bf16x8 Bl = *(const bf16x8*)&w1B[4096 + ((nt * 2 + ks) * 64 + lane) * 8];
        acc = __builtin_amdgcn_mfma_f32_16x16x32_bf16(Ah[mt][ks], Bh, acc, 0, 0, 0);
        acc = __builtin_amdgcn_mfma_f32_16x16x32_bf16(Ah[mt][ks], Bl, acc, 0, 0, 0);
        acc = __builtin_amdgcn_mfma_f32_16x16x32_bf16(Al[mt][ks], Bh, acc, 0, 0, 0);
      }
      #pragma unroll
      for (int r = 0; r < 4; r++) {
        int i = mt * 16 + rq + r;
        if (i < 25) sPre[(nt * 16 + rr) * 29 + i] = acc[r];
      }
    }
  }
  __syncthreads();

  if (tid < 200) {
    int lin = tid * 8;
    bf16x8 p8;
    #pragma unroll
    for (int e = 0; e < 8; e++) {
      int q = lin + e, ko = q / 25, v = q - ko * 25;
      p8[e] = (bf16)sPre[ko * 29 + v];
    }
    *(bf16x8*)&preB[blk * 1600 + lin] = p8;
  }
  if (tid < 64) {
    float s = 0.f, q = 0.f;
    #pragma unroll
    for (int i = 0; i < 25; i++) { float v = sPre[tid * 29 + i]; s += v; q += v * v; }
    pSum[blk * 64 + tid] = s;
    pSq [blk * 64 + tid] = q;
  }
}

// ------------------------------------------------------------------
// Kernel 5: TCN branches; preB [n][t][ch][v], zbB [b][n][t][o][v]
// ------------------------------------------------------------------
template<int D>
__device__ __forceinline__ void conv5(const float* __restrict__ sIn, const float* __restrict__ sW,
                                      float4 bias, int o4, int v, int tb, float acc[8][4])
{
  #pragma unroll
  for (int s = 0; s < 8; s++) {
    acc[s][0] = bias.x; acc[s][1] = bias.y; acc[s][2] = bias.z; acc[s][3] = bias.w;
  }
  const int NW = 8 + 4 * D;
  for (int ic = 0; ic < 16; ic++) {
    float4 wk[5];
    #pragma unroll
    for (int kt = 0; kt < 5; kt++) wk[kt] = *(const float4*)&sW[(ic * 5 + kt) * 16 + o4];
    float xw[8 + 4 * D];
    #pragma unroll
    for (int w = 0; w < NW; w++) xw[w] = sIn[(ic * 24 + (tb - 2 * D + w + 4)) * 25 + v];
    #pragma unroll
    for (int s = 0; s < 8; s++)
      #pragma unroll
      for (int kt = 0; kt < 5; kt++) {
        float xv = xw[s + kt * D];
        acc[s][0] += xv * wk[kt].x; acc[s][1] += xv * wk[kt].y;
        acc[s][2] += xv * wk[kt].z; acc[s][3] += xv * wk[kt].w;
      }
  }
}

__global__ __launch_bounds__(256, 3)
void k5_tcn_branch(const bf16* __restrict__ preB,
                   const float* __restrict__ sc1, const float* __restrict__ sh1,
                   const float* __restrict__ w2, const float* __restrict__ b2,
                   bf16* __restrict__ zbB, float* __restrict__ pSum2, float* __restrict__ pSq2)
{
  const int tt = blockIdx.x, b = blockIdx.y, n = blockIdx.z;
  const int tid = threadIdx.x, t0 = tt * 16;
  __shared__ __align__(16) float sIn[16 * 24 * 25];
  __shared__ __align__(16) float sW[16 * 5 * 16];
  __shared__ float sRedS[4][4][4], sRedQ[4][4][4];

  for (int idx = tid; idx < 1200; idx += 256) {
    int r = idx / 50, k8 = idx - r * 50;
    int gt = t0 - 4 + r;
    int lin = k8 * 8;
    if (gt >= 0 && gt < 512) {
      bf16x8 p8 = *(const bf16x8*)&preB[((n * 512 + gt) * 64 + b * 16) * 25 + lin];
      #pragma unroll
      for (int e = 0; e < 8; e++) {
        int q = lin + e, ic = q / 25, v = q - ic * 25;
        int ch = b * 16 + ic;
        sIn[(ic * 24 + r) * 25 + v] = fmaxf(sc1[ch] * (float)p8[e] + sh1[ch], 0.f);
      }
    } else {
      #pragma unroll
      for (int e = 0; e < 8; e++) {
        int q = lin + e, ic = q / 25, v = q - ic * 25;
        sIn[(ic * 24 + r) * 25 + v] = 0.f;
      }
    }
  }
  if (b < 2)
    for (int idx = tid; idx < 1280; idx += 256) {
      int o = idx / 80, rem = idx - o * 80;
      int ic = rem / 5, kt = rem - ic * 5;
      sW[(ic * 5 + kt) * 16 + o] = w2[((b * 16 + o) * 16 + ic) * 5 + kt];
    }
  __syncthreads();

  float po[4] = {0.f, 0.f, 0.f, 0.f}, pq[4] = {0.f, 0.f, 0.f, 0.f};
  if (tid < 200) {
    int tx = tid & 3, o4 = tx * 4;
    int g = tid >> 2;
    int v = g % 25, th = g / 25;
    int tb = th * 8;
    float acc[8][4];
    if (b == 0)      conv5<1>(sIn, sW, *(const float4*)&b2[o4],      o4, v, tb, acc);
    else if (b == 1) conv5<2>(sIn, sW, *(const float4*)&b2[16 + o4], o4, v, tb, acc);
    else {
      #pragma unroll
      for (int s = 0; s < 8; s++)
        #pragma unroll
        for (int j = 0; j < 4; j++) {
          int o = o4 + j, r = tb + s + 4;
          float a = sIn[(o * 24 + r - 1) * 25 + v];
          float m = sIn[(o * 24 + r    ) * 25 + v];
          float c = sIn[(o * 24 + r + 1) * 25 + v];
          acc[s][j] = fmaxf(fmaxf(a, m), c);
        }
    }
    #pragma unroll
    for (int s = 0; s < 8; s++) {
      int gt = t0 + tb + s;
      #pragma unroll
      for (int j = 0; j < 4; j++) {
        float val = acc[s][j];
        zbB[(((b * 32 + n) * 512 + gt) * 16 + (o4 + j)) * 25 + v] = (bf16)val;
        po[j] += val; pq[j] += val * val;
      }
    }
  }
  #pragma unroll
  for (int m = 4; m < 64; m <<= 1) {
    #pragma unroll
    for (int j = 0; j < 4; j++) { po[j] += __shfl_xor(po[j], m); pq[j] += __shfl_xor(pq[j], m); }
  }
  int lane = tid & 63, w = tid >> 6;
  if (lane < 4) {
    #pragma unroll
    for (int j = 0; j < 4; j++) { sRedS[w][lane][j] = po[j]; sRedQ[w][lane][j] = pq[j]; }
  }
  __syncthreads();
  if (tid < 16) {
    int o = tid, txo = o >> 2, j = o & 3;
    float s = 0.f, q = 0.f;
    #pragma unroll
    for (int ww = 0; ww < 4; ww++) { s += sRedS[ww][txo][j]; q += sRedQ[ww][txo][j]; }
    int pidx = (n * 32 + tt) * 48 + b * 16 + o;
    pSum2[pidx] = s; pSq2[pidx] = q;
  }
}

// ------------------------------------------------------------------
// Kernel 7: concat + bn + residual + relu. Block per (n, 8-t chunk).
// ------------------------------------------------------------------
__global__ __launch_bounds__(256, 8)
void k7_final(const float* __restrict__ x, const bf16* __restrict__ preB,
              const bf16* __restrict__ zbB,
              const float* __restrict__ sc1, const float* __restrict__ sh1,
              const float* __restrict__ sc2, const float* __restrict__ sh2,
              float* __restrict__ out)
{
  const int bid = blockIdx.x;            // 2048 = 32 n * 64 chunks
  const int n = bid >> 6, tc = bid & 63;
  const int t0 = tc * 8;
  for (int e = threadIdx.x; e < 12800; e += 256) {
    int ch = e / 200, r = e - ch * 200;
    int tl = r / 25, v = r - tl * 25;
    int t = t0 + tl;
    int b = ch >> 4, o = ch & 15;
    float val;
    if (b < 3) {
      val = sc2[b * 16 + o] * (float)zbB[(((b * 32 + n) * 512 + t) * 16 + o) * 25 + v]
          + sh2[b * 16 + o];
    } else {
      int ko = 48 + o;
      val = sc1[ko] * (float)preB[((n * 512 + t) * 64 + ko) * 25 + v] + sh1[ko];
    }
    int ax = (n * 64 + ch) * 12800 + t * 25 + v;
    out[ax] = fmaxf(val + x[ax], 0.f);
  }
}

// ------------------------------------------------------------------
extern "C" void kernel_launch(void* const* d_in, const int* in_sizes, int n_in,
                              void* d_out, int out_size, void* d_ws, size_t ws_size,
                              hipStream_t stream)
{
  const float* x       = (const float*)d_in[0];
  const float* topo    = (const float*)d_in[1];
  const float* ln_g    = (const float*)d_in[2];
  const float* ln_b    = (const float*)d_in[3];
  const float* qk_w    = (const float*)d_in[4];
  const float* qk_b    = (const float*)d_in[5];
  const float* convd_w = (const float*)d_in[6];
  const float* convd_b = (const float*)d_in[7];
  const float* sagc_g  = (const float*)d_in[8];
  const float* sagc_b  = (const float*)d_in[9];
  const float* w1      = (const float*)d_in[10];
  const float* b1      = (const float*)d_in[11];
  const float* bn1_g   = (const float*)d_in[12];
  const float* bn1_b   = (const float*)d_in[13];
  const float* w2      = (const float*)d_in[14];
  const float* b2      = (const float*)d_in[15];
  const float* bn2_g   = (const float*)d_in[16];
  const float* bn2_b   = (const float*)d_in[17];
  float* out = (float*)d_out;
  float* ws  = (float*)d_ws;

  bf16*  preB  = (bf16*)ws;                    // 26,214,400 bf16
  bf16*  zbB   = (bf16*)(ws + 13107200);       // 19,660,800 bf16
  float* pSum1 = ws + 22937600;                // 1,048,576
  float* pSq1  = ws + 23986176;                // 1,048,576
  float* pSum2 = ws + 25034752;                // 49,152
  float* pSq2  = ws + 25083904;                // 49,152
  float* scS   = ws + 25133056;  float* shS = scS + 64;
  float* sc1   = scS + 128;      float* sh1 = scS + 192;
  float* sc2   = scS + 256;      float* sh2 = scS + 304;
  bf16*  qkB   = (bf16*)(ws + 25133440);       // 6144 bf16
  bf16*  convB = (bf16*)(ws + 25136512);       // 12288 bf16
  bf16*  w1B   = (bf16*)(ws + 25142656);       // 8192 bf16
  float* oS1   = ws + 25146752;                // 16384
  float* oQ1   = ws + 25163136;                // 16384
  bf16*  saB   = (bf16*)d_out;                 // d_out doubles as sa scratch

  const float invN = 1.f / 409600.f;   // N*T*V

  kprepack<<<10, 256, 0, stream>>>(qk_w, convd_w, w1, qkB, convB, w1B);
  k1_sa_sagc<<<dim3(512, 32), 256, 0, stream>>>(x, topo, ln_g, ln_b, qk_b,
                                                qkB, convB, convd_b, saB, pSum1, pSq1);
  kpart<<<256, 256, 0, stream>>>(pSum1, pSq1, oS1, oQ1);
  kreduce<<<64, 256, 0, stream>>>(oS1, oQ1, 256, 64, invN, sagc_g, sagc_b, scS, shS);
  k3_ygc_pre<<<dim3(512, 32), 256, 0, stream>>>(x, saB, scS, shS, w1B, b1,
                                                preB, pSum1, pSq1);
  kpart<<<256, 256, 0, stream>>>(pSum1, pSq1, oS1, oQ1);
  kreduce<<<64, 256, 0, stream>>>(oS1, oQ1, 256, 64, invN, bn1_g, bn1_b, sc1, sh1);
  k5_tcn_branch<<<dim3(32, 3, 32), 256, 0, stream>>>(preB, sc1, sh1, w2, b2,
                                                     zbB, pSum2, pSq2);
  kreduce<<<48, 256, 0, stream>>>(pSum2, pSq2, 1024, 48, invN, bn2_g, bn2_b, sc2, sh2);
  k7_final<<<2048, 256, 0, stream>>>(x, preB, zbB, sc1, sh1, sc2, sh2, out);
}

// Round 7
// 335.445 us; speedup vs baseline: 4.0179x; 1.0857x over previous
//
#include <hip/hip_runtime.h>

// EncodingBlock — Round 7: k1 occupancy/conflict fix (other kernels = round 6).
//  * k1 LDS 31.7KB -> 21.5KB (7 blocks/CU) via liveness-colored slots:
//      slot A [0,1280): featT bf16 [64][40]          (live P1-P5)
//      slot B [1280,3008): yF f32 [25][69] (P2-P3) -> sAttn bf16 [75][40] (P4-P5)
//      slot C [3008,5512): sPart+ln (P1-P2) -> sQK [25][56] (P3-P4) -> zL bf16 [25][200] (P5-P6)
//    junk-tolerant: MFMA junk A-rows only affect discarded C rows; zL reads clamped.
//  * yF single f32 array, odd stride 69 (=5 mod 32) -> conflict-free writes/reads;
//    hi/lo bf16 split done in-register in P3.
//  * P6 writes saB directly from accumulators + shfl-reduced BN partials
//    (kills old P7 phase, one barrier, and sSa).

#define EPS 1e-5f

typedef __bf16 bf16;
typedef __bf16 bf16x8 __attribute__((ext_vector_type(8)));
typedef float f32x4 __attribute__((ext_vector_type(4)));

// ------------------------------------------------------------------
// Prepack weights to MFMA B-fragments.
// ------------------------------------------------------------------
__global__ void kprepack(const float* __restrict__ qk_w, const float* __restrict__ convd_w,
                         const float* __restrict__ w1g,
                         bf16* __restrict__ qkB, bf16* __restrict__ convB, bf16* __restrict__ w1B)
{
  int gid = blockIdx.x * 256 + threadIdx.x;
  if (gid < 384) {                       // qk: (nt,ks,lane) 3*2*64, hi/lo
    int lane = gid & 63, f = gid >> 6;
    int nt = f >> 1, ks = f & 1;
    int row = nt * 16 + (lane & 15);
    int col = ks * 32 + ((lane >> 4) * 8);
    const float* src = &qk_w[row * 64 + col];
    bf16* dh = &qkB[(f * 64 + lane) * 8];
    bf16* dl = dh + 3072;
    #pragma unroll
    for (int j = 0; j < 8; j++) {
      float w = src[j];
      bf16 h = (bf16)w;
      dh[j] = h;
      dl[j] = (bf16)(w - (float)h);
    }
  } else if (gid < 1920) {               // convd: (nt,ks,lane) 4*6*64
    int g = gid - 384;
    int lane = g & 63, f = g >> 6;
    int nt = f / 6, ks = f - nt * 6;
    int k0 = ks * 32 + ((lane >> 4) * 8);
    int h = k0 >> 6, c = k0 & 63;
    int o = nt * 16 + (lane & 15);
    const float* src = &convd_w[(h * 64 + o) * 64 + c];
    bf16* d = &convB[(f * 64 + lane) * 8];
    #pragma unroll
    for (int j = 0; j < 8; j++) d[j] = (bf16)src[j];
  } else if (gid < 2432) {               // w1: (nt,ks,lane) 4*2*64, hi/lo
    int g = gid - 1920;
    int lane = g & 63, f = g >> 6;
    int nt = f >> 1, ks = f & 1;
    int ko = nt * 16 + (lane & 15);
    int c0 = ks * 32 + ((lane >> 4) * 8);
    const float* src = &w1g[ko * 64 + c0];
    bf16* dh = &w1B[(f * 64 + lane) * 8];
    bf16* dl = dh + 4096;
    #pragma unroll
    for (int j = 0; j < 8; j++) {
      float w = src[j];
      bf16 h = (bf16)w;
      dh[j] = h;
      dl[j] = (bf16)(w - (float)h);
    }
  }
}

// ------------------------------------------------------------------
// Kernel 1: fused SelfAttention + SA_GC (pre-BN). LDS 21.5 KB -> 7/CU.
// ------------------------------------------------------------------
__global__ __launch_bounds__(256, 7)
void k1_sa_sagc(const float* __restrict__ x,
                const float* __restrict__ topo,
                const float* __restrict__ ln_g, const float* __restrict__ ln_b,
                const float* __restrict__ qk_b,
                const bf16* __restrict__ qkB, const bf16* __restrict__ convB,
                const float* __restrict__ convd_b,
                bf16* __restrict__ saB, float* __restrict__ pSum, float* __restrict__ pSq)
{
  const int t = blockIdx.x, n = blockIdx.y, tid = threadIdx.x;
  const int blk = n * 512 + t;
  const int lane = tid & 63, wave = tid >> 6;
  const int rr = lane & 15, co = (lane >> 4) * 8, rq = (lane >> 4) * 4;

  __shared__ __align__(16) float smem[5512];
  bf16*  featT  = (bf16*)smem;               // [64][40] bf16     [0,1280)
  float* yF     = smem + 1280;               // [25][69] f32      [1280,3005)  slot B
  bf16*  sAttn  = (bf16*)(smem + 1280);      // [75][40] bf16     overlay of yF (P4-P5)
  float* sPartS = smem + 3008;               // [25*4]            slot C
  float* sPartQ = smem + 3208;
  float* sLnG   = smem + 3408;               // [64]
  float* sLnB   = smem + 3472;               // [64]
  float* sQK    = smem + 3008;               // [25][56] f32      overlay (P3-P4)
  bf16*  zL     = (bf16*)(smem + 3008);      // [25][200] bf16    overlay (P5-P6)

  // P1: load x (coalesced, kept in regs), featT bf16, LN partials
  const int v = tid & 31, cb = tid >> 5;
  float xv[8];
  {
    const float* xp = &x[((n * 64 + cb) * 512 + t) * 25 + (v < 25 ? v : 0)];
    float s = 0.f, q = 0.f;
    #pragma unroll
    for (int k = 0; k < 8; k++) {
      float f = (v < 25) ? xp[k * 102400] : 0.f;   // 102400 = 8*512*25
      xv[k] = f;
      featT[(cb + 8 * k) * 40 + v] = (bf16)f;
      s += f; q += f * f;
    }
    s += __shfl_xor(s, 32); q += __shfl_xor(q, 32);
    if (lane < 32 && v < 25) { sPartS[v * 4 + wave] = s; sPartQ[v * 4 + wave] = q; }
    if (tid < 64) { sLnG[tid] = ln_g[tid]; sLnB[tid] = ln_b[tid]; }
    if (tid < 64) {
      #pragma unroll
      for (int j = 25; j < 32; j++) featT[tid * 40 + j] = (bf16)0.f;
    }
  }
  __syncthreads();

  // P2: finalize LN stats (redundant per thread) + y -> yF f32 (conflict-free)
  if (v < 25) {
    float S = sPartS[v * 4] + sPartS[v * 4 + 1] + sPartS[v * 4 + 2] + sPartS[v * 4 + 3];
    float Q = sPartQ[v * 4] + sPartQ[v * 4 + 1] + sPartQ[v * 4 + 2] + sPartQ[v * 4 + 3];
    float mu = S * (1.f / 64.f);
    float rstd = rsqrtf(Q * (1.f / 64.f) - mu * mu + EPS);
    #pragma unroll
    for (int k = 0; k < 8; k++) {
      int c = cb + 8 * k;
      yF[v * 69 + c] = (xv[k] - mu) * rstd * sLnG[c] + sLnB[c];
    }
  }
  __syncthreads();

  // P3: QK projection via MFMA; hi/lo split computed in-register from yF.
  {
    const int mt = wave & 1;
    const int r0 = mt * 16 + rr;               // rows >=25 read junk -> discarded C rows
    bf16x8 Ah[2], Al[2];
    #pragma unroll
    for (int ks = 0; ks < 2; ks++) {
      const float* yp = &yF[r0 * 69 + ks * 32 + co];
      #pragma unroll
      for (int j = 0; j < 8; j++) {
        float yv = yp[j];
        bf16 h = (bf16)yv;
        Ah[ks][j] = h;
        Al[ks][j] = (bf16)(yv - (float)h);
      }
    }
    #pragma unroll
    for (int q = 0; q < 2; q++) {
      if (wave >= 2 && q > 0) break;
      int nt = (wave < 2) ? (q * 2) : 1;
      float qb = qk_b[nt * 16 + rr];
      f32x4 acc = {qb, qb, qb, qb};
      #pragma unroll
      for (int ks = 0; ks < 2; ks++) {
        bf16x8 Bh = *(const bf16x8*)&qkB[((nt * 2 + ks) * 64 + lane) * 8];
        bf16x8 Bl = *(const bf16x8*)&qkB[3072 + ((nt * 2 + ks) * 64 + lane) * 8];
        acc = __builtin_amdgcn_mfma_f32_16x16x32_bf16(Ah[ks], Bh, acc, 0, 0, 0);
        acc = __builtin_amdgcn_mfma_f32_16x16x32_bf16(Ah[ks], Bl, acc, 0, 0, 0);
        acc = __builtin_amdgcn_mfma_f32_16x16x32_bf16(Al[ks], Bh, acc, 0, 0, 0);
      }
      #pragma unroll
      for (int r = 0; r < 4; r++) {
        int i = mt * 16 + rq + r;
        if (i < 25) sQK[i * 56 + nt * 16 + rr] = acc[r];
      }
    }
  }
  __syncthreads();

  // P4: dots + softmax + *topo -> sAttn bf16 [75][40]; 2 threads per (h,i) row
  if (tid < 150) {
    int p = tid >> 1, half = tid & 1;
    int h = p / 25, i = p - (p / 25) * 25;
    const float* qr = &sQK[i * 56 + h * 8];
    float4 qa = *(const float4*)qr, qb4 = *(const float4*)(qr + 4);
    const int j0 = half * 13;
    const int cnt = 13 - half;
    float lgv[13];
    float lmax = -3.4e38f;
    #pragma unroll
    for (int jj = 0; jj < 13; jj++) {
      int j = j0 + jj; j = j > 24 ? 24 : j;
      const float* kr = &sQK[j * 56 + 24 + h * 8];
      float4 ka = *(const float4*)kr, kb = *(const float4*)(kr + 4);
      float d = qa.x * ka.x + qa.y * ka.y + qa.z * ka.z + qa.w * ka.w
              + qb4.x * kb.x + qb4.y * kb.y + qb4.z * kb.z + qb4.w * kb.w;
      d *= 0.35355339059327373f;
      lgv[jj] = d;
      lmax = fmaxf(lmax, d);
    }
    lmax = fmaxf(lmax, __shfl_xor(lmax, 1));
    float se = 0.f;
    #pragma unroll
    for (int jj = 0; jj < 13; jj++) {
      float e = __expf(lgv[jj] - lmax);
      lgv[jj] = e;
      if (jj < cnt) se += e;
    }
    se += __shfl_xor(se, 1);
    float inv = 1.f / se;
    bf16* ar = &sAttn[(h * 25 + i) * 40];
    #pragma unroll
    for (int jj = 0; jj < 13; jj++) {
      int j = j0 + jj;
      if (jj < cnt) ar[j] = (bf16)(lgv[jj] * inv * topo[(h * 25 + i) * 25 + j]);
    }
    if (half) {
      #pragma unroll
      for (int j = 25; j < 32; j++) ar[j] = (bf16)0.f;   // K-dim pad must be zero
    }
  }
  __syncthreads();

  // P5: z = A_h @ feat via MFMA; wave owns 16 feat-cols; zL [25][200]
  {
    const int nt = wave;
    bf16x8 Bf = *(const bf16x8*)&featT[(nt * 16 + rr) * 40 + co];
    #pragma unroll
    for (int h = 0; h < 3; h++) {
      #pragma unroll
      for (int mt = 0; mt < 2; mt++) {
        // junk A rows (h*25 + mt*16+rr >= valid) stay inside slot B -> finite garbage,
        // they only affect C rows i>=25 which are discarded below.
        bf16x8 Af = *(const bf16x8*)&sAttn[(h * 25 + mt * 16 + rr) * 40 + co];
        f32x4 az = {0.f, 0.f, 0.f, 0.f};
        az = __builtin_amdgcn_mfma_f32_16x16x32_bf16(Af, Bf, az, 0, 0, 0);
        #pragma unroll
        for (int r = 0; r < 4; r++) {
          int i = mt * 16 + rq + r;
          if (i < 25) zL[i * 200 + h * 64 + nt * 16 + rr] = (bf16)az[r];
        }
      }
    }
  }
  __syncthreads();

  // P6: sa = z @ Wcat via MFMA; direct global store + shfl BN partials
  {
    const int nt = wave;
    int o = nt * 16 + rr;
    float cb2 = convd_b[o] + convd_b[64 + o] + convd_b[128 + o];
    float po = 0.f, pq = 0.f;
    #pragma unroll
    for (int mt = 0; mt < 2; mt++) {
      int zr = mt * 16 + rr;
      zr = (zr < 25) ? zr : 0;                 // clamp: stay inside zL allocation
      f32x4 acc = {cb2, cb2, cb2, cb2};
      #pragma unroll
      for (int ks = 0; ks < 6; ks++) {
        bf16x8 Az = *(const bf16x8*)&zL[zr * 200 + ks * 32 + co];
        bf16x8 Bw = *(const bf16x8*)&convB[((nt * 6 + ks) * 64 + lane) * 8];
        acc = __builtin_amdgcn_mfma_f32_16x16x32_bf16(Az, Bw, acc, 0, 0, 0);
      }
      #pragma unroll
      for (int r = 0; r < 4; r++) {
        int i = mt * 16 + rq + r;
        if (i < 25) {
          float val = acc[r];
          saB[blk * 1600 + o * 25 + i] = (bf16)val;
          po += val; pq += val * val;
        }
      }
    }
    po += __shfl_xor(po, 16); pq += __shfl_xor(pq, 16);
    po += __shfl_xor(po, 32); pq += __shfl_xor(pq, 32);
    if (lane < 16) {
      pSum[blk * 64 + o] = po;
      pSq [blk * 64 + o] = pq;
    }
  }
}

// ------------------------------------------------------------------
// kpart: coalesced first-level reduce of [16384][64] partials -> [256][64]
// ------------------------------------------------------------------
__global__ __launch_bounds__(256, 8)
void kpart(const float* __restrict__ pS, const float* __restrict__ pQ,
           float* __restrict__ oS, float* __restrict__ oQ)
{
  const int g = blockIdx.x, tid = threadIdx.x;
  const int c = tid & 63, r = tid >> 6;
  float s = 0.f, q = 0.f;
  for (int i = 0; i < 16; i++) {
    int b = g * 64 + r * 16 + i;
    s += pS[b * 64 + c]; q += pQ[b * 64 + c];
  }
  __shared__ float ls[4][64], lq[4][64];
  ls[r][c] = s; lq[r][c] = q;
  __syncthreads();
  if (tid < 64) {
    oS[g * 64 + tid] = ls[0][tid] + ls[1][tid] + ls[2][tid] + ls[3][tid];
    oQ[g * 64 + tid] = lq[0][tid] + lq[1][tid] + lq[2][tid] + lq[3][tid];
  }
}

// ------------------------------------------------------------------
// BN-stat reduce: one block per channel; partials layout [part][C]
// ------------------------------------------------------------------
__global__ __launch_bounds__(256, 4)
void kreduce(const float* __restrict__ pS, const float* __restrict__ pQ,
             int npart, int C, float invN,
             const float* __restrict__ g, const float* __restrict__ bta,
             float* __restrict__ sc, float* __restrict__ sh)
{
  int c = blockIdx.x, tid = threadIdx.x;
  float s = 0.f, q = 0.f;
  for (int i = tid; i < npart; i += 256) { s += pS[i * C + c]; q += pQ[i * C + c]; }
  #pragma unroll
  for (int m = 1; m < 64; m <<= 1) { s += __shfl_xor(s, m); q += __shfl_xor(q, m); }
  __shared__ float rs[4], rq[4];
  int w = tid >> 6;
  if ((tid & 63) == 0) { rs[w] = s; rq[w] = q; }
  __syncthreads();
  if (tid == 0) {
    float S = rs[0] + rs[1] + rs[2] + rs[3];
    float Q = rq[0] + rq[1] + rq[2] + rq[3];
    float mu = S * invN, var = Q * invN - mu * mu;
    float r = rsqrtf(var + EPS);
    sc[c] = g[c] * r;
    sh[c] = bta[c] - mu * g[c] * r;
  }
}

// ------------------------------------------------------------------
// Kernel 3: y_gc = relu(bn(sa)+x); pre = y_gc @ W1 + b1 via MFMA (hi/lo)
// ------------------------------------------------------------------
__global__ __launch_bounds__(256, 8)
void k3_ygc_pre(const float* __restrict__ x, const bf16* __restrict__ saB,
                const float* __restrict__ scS, const float* __restrict__ shS,
                const bf16* __restrict__ w1B, const float* __restrict__ b1,
                bf16* __restrict__ preB, float* __restrict__ pSum, float* __restrict__ pSq)
{
  const int t = blockIdx.x, n = blockIdx.y, tid = threadIdx.x;
  const int blk = n * 512 + t;
  const int lane = tid & 63, wave = tid >> 6;
  const int rr = lane & 15, co = (lane >> 4) * 8, rq = (lane >> 4) * 4;

  __shared__ __align__(16) float smem[3656];
  bf16*  yH   = (bf16*)smem;             // [25][72] bf16 -> [0, 900)
  bf16*  yL   = (bf16*)(smem + 900);     // [900, 1800)
  float* sPre = smem + 1800;             // [64][29] [1800, 3656)

  if (tid < 200) {
    int lin = tid * 8;
    int c = lin / 25, v = lin - c * 25;
    bf16x8 s8 = *(const bf16x8*)&saB[blk * 1600 + lin];
    #pragma unroll
    for (int e = 0; e < 8; e++) {
      float val = scS[c] * (float)s8[e] + shS[c] + x[((n * 64 + c) * 512 + t) * 25 + v];
      val = fmaxf(val, 0.f);
      bf16 h = (bf16)val;
      yH[v * 72 + c] = h;
      yL[v * 72 + c] = (bf16)(val - (float)h);
      if (++v == 25) { v = 0; c++; }
    }
  }
  __syncthreads();

  {
    const int nt = wave;  // output cols nt*16..+15
    bf16x8 Ah[2][2], Al[2][2];
    #pragma unroll
    for (int mt = 0; mt < 2; mt++) {
      int r0 = mt * 16 + rr;               // rows >=25 read junk -> discarded
      #pragma unroll
      for (int ks = 0; ks < 2; ks++) {
        Ah[mt][ks] = *(const bf16x8*)&yH[r0 * 72 + ks * 32 + co];
        Al[mt][ks] = *(const bf16x8*)&yL[r0 * 72 + ks * 32 + co];
      }
    }
    float bb = b1[nt * 16 + rr];
    #pragma unroll
    for (int mt = 0; mt < 2; mt++) {
      f32x4 acc = {bb, bb, bb, bb};
      #pragma unroll
      for (int ks = 0; ks < 2; ks++) {
        bf16x8 Bh = *(const bf16x8*)&w1B[((nt * 2 + ks) * 64 + lane) * 8];
        bf16x8 Bl = *(const bf16x8*)&w1B[4096 + ((nt * 2 + ks) * 64 + lane) * 8];
        acc = __builtin_amdgcn_mfma_f32_16x16x32_bf16(Ah[mt][ks], Bh, acc, 0, 0, 0);
        acc = __builtin_amdgcn_mfma_f32_16x16x32_bf16(Ah[mt][ks], Bl, acc, 0, 0, 0);
        acc = __builtin_amdgcn_mfma_f32_16x16x32_bf16(Al[mt][ks], Bh, acc, 0, 0, 0);
      }
      #pragma unroll
      for (int r = 0; r < 4; r++) {
        int i = mt * 16 + rq + r;
        if (i < 25) sPre[(nt * 16 + rr) * 29 + i] = acc[r];
      }
    }
  }
  __syncthreads();

  if (tid < 200) {
    int lin = tid * 8;
    bf16x8 p8;
    #pragma unroll
    for (int e = 0; e < 8; e++) {
      int q = lin + e, ko = q / 25, v = q - ko * 25;
      p8[e] = (bf16)sPre[ko * 29 + v];
    }
    *(bf16x8*)&preB[blk * 1600 + lin] = p8;
  }
  if (tid < 64) {
    float s = 0.f, q = 0.f;
    #pragma unroll
    for (int i = 0; i < 25; i++) { float v = sPre[tid * 29 + i]; s += v; q += v * v; }
    pSum[blk * 64 + tid] = s;
    pSq [blk * 64 + tid] = q;
  }
}

// ------------------------------------------------------------------
// Kernel 5: TCN branches; preB [n][t][ch][v], zbB [b][n][t][o][v]
// ------------------------------------------------------------------
template<int D>
__device__ __forceinline__ void conv5(const float* __restrict__ sIn, const float* __restrict__ sW,
                                      float4 bias, int o4, int v, int tb, float acc[8][4])
{
  #pragma unroll
  for (int s = 0; s < 8; s++) {
    acc[s][0] = bias.x; acc[s][1] = bias.y; acc[s][2] = bias.z; acc[s][3] = bias.w;
  }
  const int NW = 8 + 4 * D;
  for (int ic = 0; ic < 16; ic++) {
    float4 wk[5];
    #pragma unroll
    for (int kt = 0; kt < 5; kt++) wk[kt] = *(const float4*)&sW[(ic * 5 + kt) * 16 + o4];
    float xw[8 + 4 * D];
    #pragma unroll
    for (int w = 0; w < NW; w++) xw[w] = sIn[(ic * 24 + (tb - 2 * D + w + 4)) * 25 + v];
    #pragma unroll
    for (int s = 0; s < 8; s++)
      #pragma unroll
      for (int kt = 0; kt < 5; kt++) {
        float xv = xw[s + kt * D];
        acc[s][0] += xv * wk[kt].x; acc[s][1] += xv * wk[kt].y;
        acc[s][2] += xv * wk[kt].z; acc[s][3] += xv * wk[kt].w;
      }
  }
}

__global__ __launch_bounds__(256, 3)
void k5_tcn_branch(const bf16* __restrict__ preB,
                   const float* __restrict__ sc1, const float* __restrict__ sh1,
                   const float* __restrict__ w2, const float* __restrict__ b2,
                   bf16* __restrict__ zbB, float* __restrict__ pSum2, float* __restrict__ pSq2)
{
  const int tt = blockIdx.x, b = blockIdx.y, n = blockIdx.z;
  const int tid = threadIdx.x, t0 = tt * 16;
  __shared__ __align__(16) float sIn[16 * 24 * 25];
  __shared__ __align__(16) float sW[16 * 5 * 16];
  __shared__ float sRedS[4][4][4], sRedQ[4][4][4];

  for (int idx = tid; idx < 1200; idx += 256) {
    int r = idx / 50, k8 = idx - r * 50;
    int gt = t0 - 4 + r;
    int lin = k8 * 8;
    if (gt >= 0 && gt < 512) {
      bf16x8 p8 = *(const bf16x8*)&preB[((n * 512 + gt) * 64 + b * 16) * 25 + lin];
      #pragma unroll
      for (int e = 0; e < 8; e++) {
        int q = lin + e, ic = q / 25, v = q - ic * 25;
        int ch = b * 16 + ic;
        sIn[(ic * 24 + r) * 25 + v] = fmaxf(sc1[ch] * (float)p8[e] + sh1[ch], 0.f);
      }
    } else {
      #pragma unroll
      for (int e = 0; e < 8; e++) {
        int q = lin + e, ic = q / 25, v = q - ic * 25;
        sIn[(ic * 24 + r) * 25 + v] = 0.f;
      }
    }
  }
  if (b < 2)
    for (int idx = tid; idx < 1280; idx += 256) {
      int o = idx / 80, rem = idx - o * 80;
      int ic = rem / 5, kt = rem - ic * 5;
      sW[(ic * 5 + kt) * 16 + o] = w2[((b * 16 + o) * 16 + ic) * 5 + kt];
    }
  __syncthreads();

  float po[4] = {0.f, 0.f, 0.f, 0.f}, pq[4] = {0.f, 0.f, 0.f, 0.f};
  if (tid < 200) {
    int tx = tid & 3, o4 = tx * 4;
    int g = tid >> 2;
    int v = g % 25, th = g / 25;
    int tb = th * 8;
    float acc[8][4];
    if (b == 0)      conv5<1>(sIn, sW, *(const float4*)&b2[o4],      o4, v, tb, acc);
    else if (b == 1) conv5<2>(sIn, sW, *(const float4*)&b2[16 + o4], o4, v, tb, acc);
    else {
      #pragma unroll
      for (int s = 0; s < 8; s++)
        #pragma unroll
        for (int j = 0; j < 4; j++) {
          int o = o4 + j, r = tb + s + 4;
          float a = sIn[(o * 24 + r - 1) * 25 + v];
          float m = sIn[(o * 24 + r    ) * 25 + v];
          float c = sIn[(o * 24 + r + 1) * 25 + v];
          acc[s][j] = fmaxf(fmaxf(a, m), c);
        }
    }
    #pragma unroll
    for (int s = 0; s < 8; s++) {
      int gt = t0 + tb + s;
      #pragma unroll
      for (int j = 0; j < 4; j++) {
        float val = acc[s][j];
        zbB[(((b * 32 + n) * 512 + gt) * 16 + (o4 + j)) * 25 + v] = (bf16)val;
        po[j] += val; pq[j] += val * val;
      }
    }
  }
  #pragma unroll
  for (int m = 4; m < 64; m <<= 1) {
    #pragma unroll
    for (int j = 0; j < 4; j++) { po[j] += __shfl_xor(po[j], m); pq[j] += __shfl_xor(pq[j], m); }
  }
  int lane = tid & 63, w = tid >> 6;
  if (lane < 4) {
    #pragma unroll
    for (int j = 0; j < 4; j++) { sRedS[w][lane][j] = po[j]; sRedQ[w][lane][j] = pq[j]; }
  }
  __syncthreads();
  if (tid < 16) {
    int o = tid, txo = o >> 2, j = o & 3;
    float s = 0.f, q = 0.f;
    #pragma unroll
    for (int ww = 0; ww < 4; ww++) { s += sRedS[ww][txo][j]; q += sRedQ[ww][txo][j]; }
    int pidx = (n * 32 + tt) * 48 + b * 16 + o;
    pSum2[pidx] = s; pSq2[pidx] = q;
  }
}

// ------------------------------------------------------------------
// Kernel 7: concat + bn + residual + relu. Block per (n, 8-t chunk).
// ------------------------------------------------------------------
__global__ __launch_bounds__(256, 8)
void k7_final(const float* __restrict__ x, const bf16* __restrict__ preB,
              const bf16* __restrict__ zbB,
              const float* __restrict__ sc1, const float* __restrict__ sh1,
              const float* __restrict__ sc2, const float* __restrict__ sh2,
              float* __restrict__ out)
{
  const int bid = blockIdx.x;            // 2048 = 32 n * 64 chunks
  const int n = bid >> 6, tc = bid & 63;
  const int t0 = tc * 8;
  for (int e = threadIdx.x; e < 12800; e += 256) {
    int ch = e / 200, r = e - ch * 200;
    int tl = r / 25, v = r - tl * 25;
    int t = t0 + tl;
    int b = ch >> 4, o = ch & 15;
    float val;
    if (b < 3) {
      val = sc2[b * 16 + o] * (float)zbB[(((b * 32 + n) * 512 + t) * 16 + o) * 25 + v]
          + sh2[b * 16 + o];
    } else {
      int ko = 48 + o;
      val = sc1[ko] * (float)preB[((n * 512 + t) * 64 + ko) * 25 + v] + sh1[ko];
    }
    int ax = (n * 64 + ch) * 12800 + t * 25 + v;
    out[ax] = fmaxf(val + x[ax], 0.f);
  }
}

// ------------------------------------------------------------------
extern "C" void kernel_launch(void* const* d_in, const int* in_sizes, int n_in,
                              void* d_out, int out_size, void* d_ws, size_t ws_size,
                              hipStream_t stream)
{
  const float* x       = (const float*)d_in[0];
  const float* topo    = (const float*)d_in[1];
  const float* ln_g    = (const float*)d_in[2];
  const float* ln_b    = (const float*)d_in[3];
  const float* qk_w    = (const float*)d_in[4];
  const float* qk_b    = (const float*)d_in[5];
  const float* convd_w = (const float*)d_in[6];
  const float* convd_b = (const float*)d_in[7];
  const float* sagc_g  = (const float*)d_in[8];
  const float* sagc_b  = (const float*)d_in[9];
  const float* w1      = (const float*)d_in[10];
  const float* b1      = (const float*)d_in[11];
  const float* bn1_g   = (const float*)d_in[12];
  const float* bn1_b   = (const float*)d_in[13];
  const float* w2      = (const float*)d_in[14];
  const float* b2      = (const float*)d_in[15];
  const float* bn2_g   = (const float*)d_in[16];
  const float* bn2_b   = (const float*)d_in[17];
  float* out = (float*)d_out;
  float* ws  = (float*)d_ws;

  bf16*  preB  = (bf16*)ws;                    // 26,214,400 bf16
  bf16*  zbB   = (bf16*)(ws + 13107200);       // 19,660,800 bf16
  float* pSum1 = ws + 22937600;                // 1,048,576
  float* pSq1  = ws + 23986176;                // 1,048,576
  float* pSum2 = ws + 25034752;                // 49,152
  float* pSq2  = ws + 25083904;                // 49,152
  float* scS   = ws + 25133056;  float* shS = scS + 64;
  float* sc1   = scS + 128;      float* sh1 = scS + 192;
  float* sc2   = scS + 256;      float* sh2 = scS + 304;
  bf16*  qkB   = (bf16*)(ws + 25133440);       // 6144 bf16
  bf16*  convB = (bf16*)(ws + 25136512);       // 12288 bf16
  bf16*  w1B   = (bf16*)(ws + 25142656);       // 8192 bf16
  float* oS1   = ws + 25146752;                // 16384
  float* oQ1   = ws + 25163136;                // 16384
  bf16*  saB   = (bf16*)d_out;                 // d_out doubles as sa scratch

  const float invN = 1.f / 409600.f;   // N*T*V

  kprepack<<<10, 256, 0, stream>>>(qk_w, convd_w, w1, qkB, convB, w1B);
  k1_sa_sagc<<<dim3(512, 32), 256, 0, stream>>>(x, topo, ln_g, ln_b, qk_b,
                                                qkB, convB, convd_b, saB, pSum1, pSq1);
  kpart<<<256, 256, 0, stream>>>(pSum1, pSq1, oS1, oQ1);
  kreduce<<<64, 256, 0, stream>>>(oS1, oQ1, 256, 64, invN, sagc_g, sagc_b, scS, shS);
  k3_ygc_pre<<<dim3(512, 32), 256, 0, stream>>>(x, saB, scS, shS, w1B, b1,
                                                preB, pSum1, pSq1);
  kpart<<<256, 256, 0, stream>>>(pSum1, pSq1, oS1, oQ1);
  kreduce<<<64, 256, 0, stream>>>(oS1, oQ1, 256, 64, invN, bn1_g, bn1_b, sc1, sh1);
  k5_tcn_branch<<<dim3(32, 3, 32), 256, 0, stream>>>(preB, sc1, sh1, w2, b2,
                                                     zbB, pSum2, pSq2);
  kreduce<<<48, 256, 0, stream>>>(pSum2, pSq2, 1024, 48, invN, bn2_g, bn2_b, sc2, sh2);
  k7_final<<<2048, 256, 0, stream>>>(x, preB, zbB, sc1, sh1, sc2, sh2, out);
}